// Round 4
// baseline (5996.629 us; speedup 1.0000x reference)
//
#include <hip/hip_runtime.h>
#include <hip/hip_bf16.h>
#include <stdint.h>
#include <stddef.h>

typedef short bf16x8 __attribute__((ext_vector_type(8)));
typedef float f32x4 __attribute__((ext_vector_type(4)));
typedef int i32x4 __attribute__((ext_vector_type(4)));
typedef unsigned short u16;
typedef unsigned int u32;
typedef unsigned long long u64;

#define SCOPE_AGENT __HIP_MEMORY_SCOPE_AGENT

// ---------- helpers: fp32 -> bf16 (RNE) split ----------
__device__ __forceinline__ u16 f2bf(float x) {
  u32 u = __builtin_bit_cast(u32, x);
  u32 r = (u + 0x7fffu + ((u >> 16) & 1u)) >> 16;
  return (u16)r;
}
__device__ __forceinline__ float bf2f(u16 h) {
  u32 u = ((u32)h) << 16;
  return __builtin_bit_cast(float, u);
}
__device__ __forceinline__ void split2(float a, float b, u32& hw, u32& lw) {
  u16 ha = f2bf(a), hb = f2bf(b);
  float ra = a - bf2f(ha), rb = b - bf2f(hb);
  hw = (u32)ha | ((u32)hb << 16);
  lw = (u32)f2bf(ra) | ((u32)f2bf(rb) << 16);
}
// pack h value as (bf16_hi << 16) | bf16_lo
__device__ __forceinline__ u32 pack_hl(float v) {
  u16 hi = f2bf(v);
  u16 lo = f2bf(v - bf2f(hi));
  return ((u32)hi << 16) | (u32)lo;
}
// fast tanh: (2^(2x*log2e) - 1) / (2^(2x*log2e) + 1), clamped
__device__ __forceinline__ float tanh_fast(float x) {
  float xc = fminf(9.0f, fmaxf(-9.0f, x));
  float z = exp2f(xc * 2.8853900817779268f);  // e^{2x}
  return (z - 1.0f) * __builtin_amdgcn_rcpf(z + 1.0f);
}

// ---------- prep: transpose + bf16-split a 1024x1024 weight ----------
__global__ void wsplit(const float* __restrict__ W, u16* __restrict__ Thi, u16* __restrict__ Tlo) {
  __shared__ float tile[32][33];
  const int bx = blockIdx.x * 32;  // c base
  const int by = blockIdx.y * 32;  // k base
  const int tx = threadIdx.x, ty = threadIdx.y;  // (32,8)
#pragma unroll
  for (int r = 0; r < 4; ++r) {
    int ky = ty + 8 * r;
    tile[ky][tx] = W[(size_t)(by + ky) * 1024 + bx + tx];
  }
  __syncthreads();
#pragma unroll
  for (int r = 0; r < 4; ++r) {
    int row = ty + 8 * r;           // c-local
    float v = tile[tx][row];        // = W[by+tx][bx+row]
    u16 hi = f2bf(v);
    u16 lo = f2bf(v - bf2f(hi));
    Thi[(size_t)(bx + row) * 1024 + by + tx] = hi;
    Tlo[(size_t)(bx + row) * 1024 + by + tx] = lo;
  }
}

// ---------- prep: packed h0 broadcast buffer (parity 0) + zero flags ----------
__global__ void hinit(const float* __restrict__ h0, u32* __restrict__ hb0, int* __restrict__ flags) {
  int idx = blockIdx.x * 256 + threadIdx.x;  // 65536 total
  __hip_atomic_store(&hb0[idx], pack_hl(h0[idx]), __ATOMIC_RELAXED, SCOPE_AGENT);
  if (idx < 256) __hip_atomic_store(&flags[idx], 0, __ATOMIC_RELAXED, SCOPE_AGENT);
}

// ---------- phase 1: xw = x @ Wx + b  (bf16x3 MFMA, 128x128 tile, BK=32) ----------
#define LDT 40  // padded LDS row stride (bf16 elems)

__global__ __launch_bounds__(256, 2) void xw_gemm(
    const float* __restrict__ X, const u16* __restrict__ BThi, const u16* __restrict__ BTlo,
    const float* __restrict__ bias, float* __restrict__ out) {
  __shared__ u16 Ah[128 * LDT], Al[128 * LDT], Bh[128 * LDT], Bl[128 * LDT];
  const int tid = threadIdx.x;
  const int lane = tid & 63, wave = tid >> 6;
  const int wm = wave >> 1, wn = wave & 1;
  const int m0 = blockIdx.y * 128, n0 = blockIdx.x * 128;
  const int arow = tid >> 1, afo = (tid & 1) << 4;
  const int bcol = tid >> 1, bko = (tid & 1) << 4;
  const float* Xa = X + (size_t)(m0 + arow) * 1024 + afo;
  const u16* bhp = BThi + (size_t)(n0 + bcol) * 1024 + bko;
  const u16* blp = BTlo + (size_t)(n0 + bcol) * 1024 + bko;

  f32x4 acc[4][4] = {};

  const int aoff = (wm * 64 + (lane & 15)) * LDT + ((lane >> 4) << 3);
  const int boff = (wn * 64 + (lane & 15)) * LDT + ((lane >> 4) << 3);

  for (int k0 = 0; k0 < 1024; k0 += 32) {
    const float4* xp = (const float4*)(Xa + k0);
    float4 f0 = xp[0], f1 = xp[1], f2 = xp[2], f3 = xp[3];
    i32x4 gbh0 = *(const i32x4*)(bhp + k0);
    i32x4 gbh1 = *(const i32x4*)(bhp + k0 + 8);
    i32x4 gbl0 = *(const i32x4*)(blp + k0);
    i32x4 gbl1 = *(const i32x4*)(blp + k0 + 8);
    u32 hw0, hw1, hw2, hw3, hw4, hw5, hw6, hw7;
    u32 lw0, lw1, lw2, lw3, lw4, lw5, lw6, lw7;
    split2(f0.x, f0.y, hw0, lw0); split2(f0.z, f0.w, hw1, lw1);
    split2(f1.x, f1.y, hw2, lw2); split2(f1.z, f1.w, hw3, lw3);
    split2(f2.x, f2.y, hw4, lw4); split2(f2.z, f2.w, hw5, lw5);
    split2(f3.x, f3.y, hw6, lw6); split2(f3.z, f3.w, hw7, lw7);
    __syncthreads();
    *(i32x4*)&Ah[arow * LDT + afo]     = i32x4{(int)hw0, (int)hw1, (int)hw2, (int)hw3};
    *(i32x4*)&Ah[arow * LDT + afo + 8] = i32x4{(int)hw4, (int)hw5, (int)hw6, (int)hw7};
    *(i32x4*)&Al[arow * LDT + afo]     = i32x4{(int)lw0, (int)lw1, (int)lw2, (int)lw3};
    *(i32x4*)&Al[arow * LDT + afo + 8] = i32x4{(int)lw4, (int)lw5, (int)lw6, (int)lw7};
    *(i32x4*)&Bh[bcol * LDT + bko]     = gbh0;
    *(i32x4*)&Bh[bcol * LDT + bko + 8] = gbh1;
    *(i32x4*)&Bl[bcol * LDT + bko]     = gbl0;
    *(i32x4*)&Bl[bcol * LDT + bko + 8] = gbl1;
    __syncthreads();

    bf16x8 a_h[4], a_l[4], b_h[4], b_l[4];
#pragma unroll
    for (int i = 0; i < 4; ++i) {
      a_h[i] = *(const bf16x8*)(Ah + aoff + i * 16 * LDT);
      a_l[i] = *(const bf16x8*)(Al + aoff + i * 16 * LDT);
      b_h[i] = *(const bf16x8*)(Bh + boff + i * 16 * LDT);
      b_l[i] = *(const bf16x8*)(Bl + boff + i * 16 * LDT);
    }
#pragma unroll
    for (int i = 0; i < 4; ++i)
#pragma unroll
      for (int j = 0; j < 4; ++j)
        acc[i][j] = __builtin_amdgcn_mfma_f32_16x16x32_bf16(a_h[i], b_h[j], acc[i][j], 0, 0, 0);
#pragma unroll
    for (int i = 0; i < 4; ++i)
#pragma unroll
      for (int j = 0; j < 4; ++j)
        acc[i][j] = __builtin_amdgcn_mfma_f32_16x16x32_bf16(a_h[i], b_l[j], acc[i][j], 0, 0, 0);
#pragma unroll
    for (int i = 0; i < 4; ++i)
#pragma unroll
      for (int j = 0; j < 4; ++j)
        acc[i][j] = __builtin_amdgcn_mfma_f32_16x16x32_bf16(a_l[i], b_h[j], acc[i][j], 0, 0, 0);
  }
  const int ccol = n0 + wn * 64 + (lane & 15);
  const int crow = m0 + wm * 64 + ((lane >> 4) << 2);
#pragma unroll
  for (int j = 0; j < 4; ++j) {
    float bv = bias[ccol + j * 16];
#pragma unroll
    for (int i = 0; i < 4; ++i)
#pragma unroll
      for (int r = 0; r < 4; ++r)
        out[(size_t)(crow + i * 16 + r) * 1024 + ccol + j * 16] = acc[i][j][r] + bv;
  }
}

// ---------- phase 2: sequential scan, split-K 4-wave WGs ----------
// 256 WGs x 256 threads. WG (g,c): rows [g*16,g*16+16), cols [c*16,c*16+16).
// Wave w handles K-quarter [w*256,(w+1)*256): B slice (16 frags hi+lo = 64 VGPR)
// in registers, pulls 16KB of the h slab (32 u64 uncached loads, all in
// flight), 24 MFMAs. Partials reduced through a tiny double-buffered LDS
// buffer; wave 0 adds xw, tanh, publishes h + flag. d_out stores after flag.
__global__ __launch_bounds__(256, 1) void rnn_scan(
    const u16* __restrict__ WThi, const u16* __restrict__ WTlo,
    float* __restrict__ out,
    u32* __restrict__ hb0, u32* __restrict__ hb1,
    int* __restrict__ flags) {
  __shared__ f32x4 Red[2][3][64];  // [parity][wave-1][lane]
  const int tid = threadIdx.x;
  const int lane = tid & 63, w = tid >> 6;  // w = K-quarter
  const int c = blockIdx.x & 63, g = blockIdx.x >> 6;
  const int colL = lane & 15, q = lane >> 4;
  const int col = c * 16 + colL;
  const int fb = g * 64;

  // B fragments for this wave's K-quarter -> registers (once)
  bf16x8 Bh[8], Bl[8];
  {
    const u16* bhp = WThi + (size_t)col * 1024 + w * 256 + (q << 3);
    const u16* blp = WTlo + (size_t)col * 1024 + w * 256 + (q << 3);
#pragma unroll
    for (int kk = 0; kk < 8; ++kk) {
      Bh[kk] = *(const bf16x8*)(bhp + kk * 32);
      Bl[kk] = *(const bf16x8*)(blp + kk * 32);
    }
  }

  // A pull base (u64 index): row = g*16+colL, k-quarter w, k-offset q*8
  const size_t abase = (size_t)(g * 16 + colL) * 512 + w * 128 + (q << 2);
  // wave0 publish base (u32 index): rows g*16+q*4+r, col
  const size_t hbase = (size_t)(g * 16 + (q << 2)) * 1024 + col;

  for (int s = 0; s < 512; ++s) {
    const size_t obase = ((size_t)(g * 16 + (q << 2)) * 512 + s) * 1024 + col;
    float xw0 = 0.f, xw1 = 0.f, xw2 = 0.f, xw3 = 0.f;
    if (w == 0) {  // prefetch xw (cached) before the poll
      xw0 = out[obase];
      xw1 = out[obase + (size_t)1 * 512 * 1024];
      xw2 = out[obase + (size_t)2 * 512 * 1024];
      xw3 = out[obase + (size_t)3 * 512 * 1024];
      asm volatile("" : "+v"(xw0), "+v"(xw1), "+v"(xw2), "+v"(xw3));  // pin issue before poll
    }

    // wait for the 64 producers of this row-group
    while (!__all(__hip_atomic_load(&flags[fb + lane], __ATOMIC_RELAXED, SCOPE_AGENT) >= s))
      __builtin_amdgcn_s_sleep(1);
    asm volatile("" ::: "memory");

    const u64* pa = (const u64*)((s & 1) ? hb1 : hb0) + abase;
    u32* ob = (s & 1) ? hb0 : hb1;

    f32x4 a0 = {}, a1 = {}, a2 = {};
#pragma unroll
    for (int kk = 0; kk < 8; ++kk) {
      u64 w0 = __hip_atomic_load(pa + (size_t)kk * 16 + 0, __ATOMIC_RELAXED, SCOPE_AGENT);
      u64 w1 = __hip_atomic_load(pa + (size_t)kk * 16 + 1, __ATOMIC_RELAXED, SCOPE_AGENT);
      u64 w2 = __hip_atomic_load(pa + (size_t)kk * 16 + 2, __ATOMIC_RELAXED, SCOPE_AGENT);
      u64 w3 = __hip_atomic_load(pa + (size_t)kk * 16 + 3, __ATOMIC_RELAXED, SCOPE_AGENT);
      i32x4 ahv, alv;
      ahv[0] = (int)__builtin_amdgcn_perm((u32)(w0 >> 32), (u32)w0, 0x07060302u);
      alv[0] = (int)__builtin_amdgcn_perm((u32)(w0 >> 32), (u32)w0, 0x05040100u);
      ahv[1] = (int)__builtin_amdgcn_perm((u32)(w1 >> 32), (u32)w1, 0x07060302u);
      alv[1] = (int)__builtin_amdgcn_perm((u32)(w1 >> 32), (u32)w1, 0x05040100u);
      ahv[2] = (int)__builtin_amdgcn_perm((u32)(w2 >> 32), (u32)w2, 0x07060302u);
      alv[2] = (int)__builtin_amdgcn_perm((u32)(w2 >> 32), (u32)w2, 0x05040100u);
      ahv[3] = (int)__builtin_amdgcn_perm((u32)(w3 >> 32), (u32)w3, 0x07060302u);
      alv[3] = (int)__builtin_amdgcn_perm((u32)(w3 >> 32), (u32)w3, 0x05040100u);
      bf16x8 ah = __builtin_bit_cast(bf16x8, ahv);
      bf16x8 al = __builtin_bit_cast(bf16x8, alv);
      a0 = __builtin_amdgcn_mfma_f32_16x16x32_bf16(ah, Bh[kk], a0, 0, 0, 0);
      a1 = __builtin_amdgcn_mfma_f32_16x16x32_bf16(ah, Bl[kk], a1, 0, 0, 0);
      a2 = __builtin_amdgcn_mfma_f32_16x16x32_bf16(al, Bh[kk], a2, 0, 0, 0);
    }
    f32x4 p = a0 + a1 + a2;

    if (w > 0) Red[s & 1][w - 1][lane] = p;
    __syncthreads();

    if (w == 0) {
      f32x4 sum = p + Red[s & 1][0][lane] + Red[s & 1][1][lane] + Red[s & 1][2][lane];
      float h0v = tanh_fast(xw0 + sum[0]);
      float h1v = tanh_fast(xw1 + sum[1]);
      float h2v = tanh_fast(xw2 + sum[2]);
      float h3v = tanh_fast(xw3 + sum[3]);
      __hip_atomic_store(&ob[hbase],                     pack_hl(h0v), __ATOMIC_RELAXED, SCOPE_AGENT);
      __hip_atomic_store(&ob[hbase + 1024],              pack_hl(h1v), __ATOMIC_RELAXED, SCOPE_AGENT);
      __hip_atomic_store(&ob[hbase + 2048],              pack_hl(h2v), __ATOMIC_RELAXED, SCOPE_AGENT);
      __hip_atomic_store(&ob[hbase + 3072],              pack_hl(h3v), __ATOMIC_RELAXED, SCOPE_AGENT);
      // release: drain publish stores, then flag
      asm volatile("s_waitcnt vmcnt(0)" ::: "memory");
      if (lane == 0)
        __hip_atomic_store(&flags[fb + c], s + 1, __ATOMIC_RELAXED, SCOPE_AGENT);
      // d_out stores off the critical path (cached, drained by next step's vmcnt)
      out[obase]                           = h0v;
      out[obase + (size_t)1 * 512 * 1024]  = h1v;
      out[obase + (size_t)2 * 512 * 1024]  = h2v;
      out[obase + (size_t)3 * 512 * 1024]  = h3v;
    }
  }
}

// ---------- launch ----------
extern "C" void kernel_launch(void* const* d_in, const int* in_sizes, int n_in,
                              void* d_out, int out_size, void* d_ws, size_t ws_size,
                              hipStream_t stream) {
  const float* x    = (const float*)d_in[0];
  const float* h0   = (const float*)d_in[1];
  const float* Wx   = (const float*)d_in[2];
  const float* Wh   = (const float*)d_in[3];
  const float* bias = (const float*)d_in[4];
  float* out = (float*)d_out;
  char* ws = (char*)d_ws;

  const size_t MB2 = (size_t)1 << 21;
  u16* WxThi = (u16*)(ws);
  u16* WxTlo = (u16*)(ws + MB2);
  u16* WhThi = (u16*)(ws + 2 * MB2);
  u16* WhTlo = (u16*)(ws + 3 * MB2);
  u32* hb0   = (u32*)(ws + 4 * MB2);
  u32* hb1   = (u32*)(ws + 4 * MB2 + 65536 * sizeof(u32));
  int* flags = (int*)(ws + 4 * MB2 + 2 * 65536 * sizeof(u32));

  wsplit<<<dim3(32, 32), dim3(32, 8), 0, stream>>>(Wx, WxThi, WxTlo);
  wsplit<<<dim3(32, 32), dim3(32, 8), 0, stream>>>(Wh, WhThi, WhTlo);
  hinit<<<256, 256, 0, stream>>>(h0, hb0, flags);
  xw_gemm<<<dim3(8, 256), 256, 0, stream>>>(x, WxThi, WxTlo, bias, out);
  rnn_scan<<<256, 256, 0, stream>>>(WhThi, WhTlo, out, hb0, hb1, flags);
}

// Round 5
// 2182.330 us; speedup vs baseline: 2.7478x; 2.7478x over previous
//
#include <hip/hip_runtime.h>
#include <hip/hip_bf16.h>
#include <stdint.h>
#include <stddef.h>

typedef short bf16x8 __attribute__((ext_vector_type(8)));
typedef float f32x4 __attribute__((ext_vector_type(4)));
typedef int i32x4 __attribute__((ext_vector_type(4)));
typedef unsigned short u16;
typedef unsigned int u32;
typedef unsigned long long u64;

#define SCOPE_AGENT __HIP_MEMORY_SCOPE_AGENT

// ---------- helpers: fp32 -> bf16 (RNE) split ----------
__device__ __forceinline__ u16 f2bf(float x) {
  u32 u = __builtin_bit_cast(u32, x);
  u32 r = (u + 0x7fffu + ((u >> 16) & 1u)) >> 16;
  return (u16)r;
}
__device__ __forceinline__ float bf2f(u16 h) {
  u32 u = ((u32)h) << 16;
  return __builtin_bit_cast(float, u);
}
__device__ __forceinline__ void split2(float a, float b, u32& hw, u32& lw) {
  u16 ha = f2bf(a), hb = f2bf(b);
  float ra = a - bf2f(ha), rb = b - bf2f(hb);
  hw = (u32)ha | ((u32)hb << 16);
  lw = (u32)f2bf(ra) | ((u32)f2bf(rb) << 16);
}
// pack h value as (bf16_hi << 16) | bf16_lo
__device__ __forceinline__ u32 pack_hl(float v) {
  u16 hi = f2bf(v);
  u16 lo = f2bf(v - bf2f(hi));
  return ((u32)hi << 16) | (u32)lo;
}
// fast tanh
__device__ __forceinline__ float tanh_fast(float x) {
  float xc = fminf(9.0f, fmaxf(-9.0f, x));
  float z = exp2f(xc * 2.8853900817779268f);  // e^{2x}
  return (z - 1.0f) * __builtin_amdgcn_rcpf(z + 1.0f);
}

// ---------- prep: transpose + bf16-split a 1024x1024 weight ----------
__global__ void wsplit(const float* __restrict__ W, u16* __restrict__ Thi, u16* __restrict__ Tlo) {
  __shared__ float tile[32][33];
  const int bx = blockIdx.x * 32;  // c base
  const int by = blockIdx.y * 32;  // k base
  const int tx = threadIdx.x, ty = threadIdx.y;  // (32,8)
#pragma unroll
  for (int r = 0; r < 4; ++r) {
    int ky = ty + 8 * r;
    tile[ky][tx] = W[(size_t)(by + ky) * 1024 + bx + tx];
  }
  __syncthreads();
#pragma unroll
  for (int r = 0; r < 4; ++r) {
    int row = ty + 8 * r;           // c-local
    float v = tile[tx][row];        // = W[by+tx][bx+row]
    u16 hi = f2bf(v);
    u16 lo = f2bf(v - bf2f(hi));
    Thi[(size_t)(bx + row) * 1024 + by + tx] = hi;
    Tlo[(size_t)(bx + row) * 1024 + by + tx] = lo;
  }
}

// ---------- prep: h0 into block-fragment layout (parity 0) + zero flags ----------
// Slab per group g: u64 H[8192]; word for (row,kp) [kp = k/2] at
//   I = (kp>>4)*256 + (kp&3)*64 + ((kp>>2)&3)*16 + row
// so that consumer wave w, k-step t, load j2 reads u64 at (w*4+t)*256 + j2*64 + lane
// (dense 512B per 64-lane load).
__global__ void hinit(const float* __restrict__ h0, u64* __restrict__ hb0, int* __restrict__ flags) {
  int i = blockIdx.x * 256 + threadIdx.x;  // 0..32767
  int g = i >> 13, li = i & 8191;
  int Bb = li >> 8, rem = li & 255;
  int j2 = rem >> 6, q = (rem >> 4) & 3, row = rem & 15;
  int kp = Bb * 16 + q * 4 + j2, k = kp * 2;
  int n = g * 16 + row;
  u64 val = (u64)pack_hl(h0[n * 1024 + k]) | ((u64)pack_hl(h0[n * 1024 + k + 1]) << 32);
  __hip_atomic_store(&hb0[i], val, __ATOMIC_RELAXED, SCOPE_AGENT);
  if (i < 64) __hip_atomic_store(&flags[i], 0, __ATOMIC_RELAXED, SCOPE_AGENT);
}

// ---------- phase 1: xw = x @ Wx + b  (bf16x3 MFMA, 128x128 tile, BK=32) ----------
#define LDT 40  // padded LDS row stride (bf16 elems)

__global__ __launch_bounds__(256, 2) void xw_gemm(
    const float* __restrict__ X, const u16* __restrict__ BThi, const u16* __restrict__ BTlo,
    const float* __restrict__ bias, float* __restrict__ out) {
  __shared__ u16 Ah[128 * LDT], Al[128 * LDT], Bh[128 * LDT], Bl[128 * LDT];
  const int tid = threadIdx.x;
  const int lane = tid & 63, wave = tid >> 6;
  const int wm = wave >> 1, wn = wave & 1;
  const int m0 = blockIdx.y * 128, n0 = blockIdx.x * 128;
  const int arow = tid >> 1, afo = (tid & 1) << 4;
  const int bcol = tid >> 1, bko = (tid & 1) << 4;
  const float* Xa = X + (size_t)(m0 + arow) * 1024 + afo;
  const u16* bhp = BThi + (size_t)(n0 + bcol) * 1024 + bko;
  const u16* blp = BTlo + (size_t)(n0 + bcol) * 1024 + bko;

  f32x4 acc[4][4] = {};

  const int aoff = (wm * 64 + (lane & 15)) * LDT + ((lane >> 4) << 3);
  const int boff = (wn * 64 + (lane & 15)) * LDT + ((lane >> 4) << 3);

  for (int k0 = 0; k0 < 1024; k0 += 32) {
    const float4* xp = (const float4*)(Xa + k0);
    float4 f0 = xp[0], f1 = xp[1], f2 = xp[2], f3 = xp[3];
    i32x4 gbh0 = *(const i32x4*)(bhp + k0);
    i32x4 gbh1 = *(const i32x4*)(bhp + k0 + 8);
    i32x4 gbl0 = *(const i32x4*)(blp + k0);
    i32x4 gbl1 = *(const i32x4*)(blp + k0 + 8);
    u32 hw0, hw1, hw2, hw3, hw4, hw5, hw6, hw7;
    u32 lw0, lw1, lw2, lw3, lw4, lw5, lw6, lw7;
    split2(f0.x, f0.y, hw0, lw0); split2(f0.z, f0.w, hw1, lw1);
    split2(f1.x, f1.y, hw2, lw2); split2(f1.z, f1.w, hw3, lw3);
    split2(f2.x, f2.y, hw4, lw4); split2(f2.z, f2.w, hw5, lw5);
    split2(f3.x, f3.y, hw6, lw6); split2(f3.z, f3.w, hw7, lw7);
    __syncthreads();
    *(i32x4*)&Ah[arow * LDT + afo]     = i32x4{(int)hw0, (int)hw1, (int)hw2, (int)hw3};
    *(i32x4*)&Ah[arow * LDT + afo + 8] = i32x4{(int)hw4, (int)hw5, (int)hw6, (int)hw7};
    *(i32x4*)&Al[arow * LDT + afo]     = i32x4{(int)lw0, (int)lw1, (int)lw2, (int)lw3};
    *(i32x4*)&Al[arow * LDT + afo + 8] = i32x4{(int)lw4, (int)lw5, (int)lw6, (int)lw7};
    *(i32x4*)&Bh[bcol * LDT + bko]     = gbh0;
    *(i32x4*)&Bh[bcol * LDT + bko + 8] = gbh1;
    *(i32x4*)&Bl[bcol * LDT + bko]     = gbl0;
    *(i32x4*)&Bl[bcol * LDT + bko + 8] = gbl1;
    __syncthreads();

    bf16x8 a_h[4], a_l[4], b_h[4], b_l[4];
#pragma unroll
    for (int i = 0; i < 4; ++i) {
      a_h[i] = *(const bf16x8*)(Ah + aoff + i * 16 * LDT);
      a_l[i] = *(const bf16x8*)(Al + aoff + i * 16 * LDT);
      b_h[i] = *(const bf16x8*)(Bh + boff + i * 16 * LDT);
      b_l[i] = *(const bf16x8*)(Bl + boff + i * 16 * LDT);
    }
#pragma unroll
    for (int i = 0; i < 4; ++i)
#pragma unroll
      for (int j = 0; j < 4; ++j)
        acc[i][j] = __builtin_amdgcn_mfma_f32_16x16x32_bf16(a_h[i], b_h[j], acc[i][j], 0, 0, 0);
#pragma unroll
    for (int i = 0; i < 4; ++i)
#pragma unroll
      for (int j = 0; j < 4; ++j)
        acc[i][j] = __builtin_amdgcn_mfma_f32_16x16x32_bf16(a_h[i], b_l[j], acc[i][j], 0, 0, 0);
#pragma unroll
    for (int i = 0; i < 4; ++i)
#pragma unroll
      for (int j = 0; j < 4; ++j)
        acc[i][j] = __builtin_amdgcn_mfma_f32_16x16x32_bf16(a_l[i], b_h[j], acc[i][j], 0, 0, 0);
  }
  const int ccol = n0 + wn * 64 + (lane & 15);
  const int crow = m0 + wm * 64 + ((lane >> 4) << 2);
#pragma unroll
  for (int j = 0; j < 4; ++j) {
    float bv = bias[ccol + j * 16];
#pragma unroll
    for (int i = 0; i < 4; ++i)
#pragma unroll
      for (int r = 0; r < 4; ++r)
        out[(size_t)(crow + i * 16 + r) * 1024 + ccol + j * 16] = acc[i][j][r] + bv;
  }
}

// ---------- phase 2: sequential scan ----------
// 64 WGs x 512 threads (8 waves). WG (g,cw): rows [16g,16g+16), cols [64cw,64cw+64).
// Wave w owns K-eighth [w*128,(w+1)*128): B (4 col-tiles x 4 k-steps, hi+lo) pinned
// in 128 VGPRs via inline-asm loads; pulls its slab eighth as 16 dense uncached
// u64 loads/lane; 48 MFMA; partials reduced in LDS; all 512 threads finish 2
// outputs each (xw + tanh + publish + d_out); vmcnt drain; one flag per WG.
__global__ __launch_bounds__(512) void rnn_scan(
    const u16* __restrict__ WThi, const u16* __restrict__ WTlo,
    float* __restrict__ out,
    u64* __restrict__ hb0, u64* __restrict__ hb1,
    int* __restrict__ flags) {
  __shared__ float Red[8][1024];
  const int tid = threadIdx.x;
  const int lane = tid & 63, w = tid >> 6;   // w = K-eighth
  const int cw = blockIdx.x & 15, g = blockIdx.x >> 4;
  const int colL = lane & 15, q = lane >> 4;
  const int fb = g * 16;

  // ---- B -> registers via inline asm (cannot be rematerialized) ----
  i32x4 Bh_[4][4], Bl_[4][4];
#pragma unroll
  for (int ct = 0; ct < 4; ++ct) {
    const u16* bhp = WThi + (size_t)(cw * 64 + ct * 16 + colL) * 1024 + w * 128 + (q << 3);
    const u16* blp = WTlo + (size_t)(cw * 64 + ct * 16 + colL) * 1024 + w * 128 + (q << 3);
#pragma unroll
    for (int t = 0; t < 4; ++t) {
      asm volatile("global_load_dwordx4 %0, %1, off" : "=v"(Bh_[ct][t]) : "v"(bhp + t * 32));
      asm volatile("global_load_dwordx4 %0, %1, off" : "=v"(Bl_[ct][t]) : "v"(blp + t * 32));
    }
  }
  asm volatile("s_waitcnt vmcnt(0)" ::: "memory");
  __builtin_amdgcn_sched_barrier(0);

  const int pwidx = fb + 2 * w + (lane & 1);  // this wave's 2 producers

  // final-phase constants: thread handles outputs (frow, fcc), (frow, fcc+1)
  const int frow = tid >> 5;          // 0..15
  const int fcc = (tid & 31) * 2;     // 0..62
  const int kp = cw * 32 + (tid & 31);
  const size_t pubI = (size_t)(kp >> 4) * 256 + (kp & 3) * 64 + (((kp >> 2) & 3) * 16) + frow;
  const size_t orow = ((size_t)(g * 16 + frow) * 512) * 1024 + cw * 64 + fcc;
  const size_t gbase = (size_t)g * 8192;

  for (int s = 0; s < 512; ++s) {
    // wait for this wave's 2 producers to have published h_s
    while (!__all(__hip_atomic_load(&flags[pwidx], __ATOMIC_RELAXED, SCOPE_AGENT) >= s))
      __builtin_amdgcn_s_sleep(1);
    asm volatile("" ::: "memory");

    // dense uncached pull of this wave's slab eighth: 16 u64 loads, 512B/instr
    const u64* src = ((s & 1) ? hb1 : hb0) + gbase + (size_t)w * 1024 + lane;
    u64 hw_[16];
#pragma unroll
    for (int t = 0; t < 4; ++t)
#pragma unroll
      for (int j2 = 0; j2 < 4; ++j2)
        hw_[t * 4 + j2] = __hip_atomic_load(src + t * 256 + j2 * 64, __ATOMIC_RELAXED, SCOPE_AGENT);

    // xw prefetch (cached) — overlaps the pull latency
    const size_t oidx = orow + (size_t)s * 1024;
    float2 xwv = *(const float2*)&out[oidx];

    f32x4 acc[4] = {};
#pragma unroll
    for (int t = 0; t < 4; ++t) {
      u64 w0 = hw_[t * 4 + 0], w1 = hw_[t * 4 + 1], w2 = hw_[t * 4 + 2], w3 = hw_[t * 4 + 3];
      i32x4 ahv, alv;
      ahv[0] = (int)__builtin_amdgcn_perm((u32)(w0 >> 32), (u32)w0, 0x07060302u);
      alv[0] = (int)__builtin_amdgcn_perm((u32)(w0 >> 32), (u32)w0, 0x05040100u);
      ahv[1] = (int)__builtin_amdgcn_perm((u32)(w1 >> 32), (u32)w1, 0x07060302u);
      alv[1] = (int)__builtin_amdgcn_perm((u32)(w1 >> 32), (u32)w1, 0x05040100u);
      ahv[2] = (int)__builtin_amdgcn_perm((u32)(w2 >> 32), (u32)w2, 0x07060302u);
      alv[2] = (int)__builtin_amdgcn_perm((u32)(w2 >> 32), (u32)w2, 0x05040100u);
      ahv[3] = (int)__builtin_amdgcn_perm((u32)(w3 >> 32), (u32)w3, 0x07060302u);
      alv[3] = (int)__builtin_amdgcn_perm((u32)(w3 >> 32), (u32)w3, 0x05040100u);
      bf16x8 ah = __builtin_bit_cast(bf16x8, ahv);
      bf16x8 al = __builtin_bit_cast(bf16x8, alv);
#pragma unroll
      for (int ct = 0; ct < 4; ++ct) {
        acc[ct] = __builtin_amdgcn_mfma_f32_16x16x32_bf16(al, __builtin_bit_cast(bf16x8, Bh_[ct][t]), acc[ct], 0, 0, 0);
        acc[ct] = __builtin_amdgcn_mfma_f32_16x16x32_bf16(ah, __builtin_bit_cast(bf16x8, Bl_[ct][t]), acc[ct], 0, 0, 0);
        acc[ct] = __builtin_amdgcn_mfma_f32_16x16x32_bf16(ah, __builtin_bit_cast(bf16x8, Bh_[ct][t]), acc[ct], 0, 0, 0);
      }
    }

    // partials -> LDS  (row_local = q*4+r, col_local = ct*16+colL)
#pragma unroll
    for (int ct = 0; ct < 4; ++ct)
#pragma unroll
      for (int r = 0; r < 4; ++r)
        Red[w][(q * 4 + r) * 64 + ct * 16 + colL] = acc[ct][r];
    __syncthreads();

    // final: each thread reduces 8 partials for its 2 outputs
    float s0 = xwv.x, s1 = xwv.y;
#pragma unroll
    for (int ww = 0; ww < 8; ++ww) {
      float2 pr = *(const float2*)&Red[ww][frow * 64 + fcc];
      s0 += pr.x; s1 += pr.y;
    }
    float h0v = tanh_fast(s0), h1v = tanh_fast(s1);
    u64* ob = ((s & 1) ? hb0 : hb1) + gbase;
    u64 val = (u64)pack_hl(h0v) | ((u64)pack_hl(h1v) << 32);
    __hip_atomic_store(ob + pubI, val, __ATOMIC_RELAXED, SCOPE_AGENT);
    *(float2*)&out[oidx] = make_float2(h0v, h1v);

    // release: drain publish stores, barrier (all waves drained + Red reads done),
    // then one flag for the WG
    asm volatile("s_waitcnt vmcnt(0)" ::: "memory");
    __syncthreads();
    if (tid == 0)
      __hip_atomic_store(&flags[fb + cw], s + 1, __ATOMIC_RELAXED, SCOPE_AGENT);
  }
}

// ---------- launch ----------
extern "C" void kernel_launch(void* const* d_in, const int* in_sizes, int n_in,
                              void* d_out, int out_size, void* d_ws, size_t ws_size,
                              hipStream_t stream) {
  const float* x    = (const float*)d_in[0];
  const float* h0   = (const float*)d_in[1];
  const float* Wx   = (const float*)d_in[2];
  const float* Wh   = (const float*)d_in[3];
  const float* bias = (const float*)d_in[4];
  float* out = (float*)d_out;
  char* ws = (char*)d_ws;

  const size_t MB2 = (size_t)1 << 21;
  u16* WxThi = (u16*)(ws);
  u16* WxTlo = (u16*)(ws + MB2);
  u16* WhThi = (u16*)(ws + 2 * MB2);
  u16* WhTlo = (u16*)(ws + 3 * MB2);
  u64* hb0   = (u64*)(ws + 4 * MB2);
  u64* hb1   = (u64*)(ws + 4 * MB2 + 32768 * sizeof(u64));
  int* flags = (int*)(ws + 4 * MB2 + 2 * 32768 * sizeof(u64));

  wsplit<<<dim3(32, 32), dim3(32, 8), 0, stream>>>(Wx, WxThi, WxTlo);
  wsplit<<<dim3(32, 32), dim3(32, 8), 0, stream>>>(Wh, WhThi, WhTlo);
  hinit<<<128, 256, 0, stream>>>(h0, hb0, flags);
  xw_gemm<<<dim3(8, 256), 256, 0, stream>>>(x, WxThi, WxTlo, bias, out);
  rnn_scan<<<64, 512, 0, stream>>>(WhThi, WhTlo, out, hb0, hb1, flags);
}

// Round 6
// 2161.679 us; speedup vs baseline: 2.7741x; 1.0096x over previous
//
#include <hip/hip_runtime.h>
#include <hip/hip_bf16.h>
#include <stdint.h>
#include <stddef.h>

typedef short bf16x8 __attribute__((ext_vector_type(8)));
typedef float f32x4 __attribute__((ext_vector_type(4)));
typedef int i32x4 __attribute__((ext_vector_type(4)));
typedef unsigned short u16;
typedef unsigned int u32;
typedef unsigned long long u64;

#define SCOPE_AGENT __HIP_MEMORY_SCOPE_AGENT

// ---------- helpers: fp32 -> bf16 (RNE) split ----------
__device__ __forceinline__ u16 f2bf(float x) {
  u32 u = __builtin_bit_cast(u32, x);
  u32 r = (u + 0x7fffu + ((u >> 16) & 1u)) >> 16;
  return (u16)r;
}
__device__ __forceinline__ float bf2f(u16 h) {
  u32 u = ((u32)h) << 16;
  return __builtin_bit_cast(float, u);
}
__device__ __forceinline__ void split2(float a, float b, u32& hw, u32& lw) {
  u16 ha = f2bf(a), hb = f2bf(b);
  float ra = a - bf2f(ha), rb = b - bf2f(hb);
  hw = (u32)ha | ((u32)hb << 16);
  lw = (u32)f2bf(ra) | ((u32)f2bf(rb) << 16);
}
// pack h value as (bf16_hi << 16) | bf16_lo
__device__ __forceinline__ u32 pack_hl(float v) {
  u16 hi = f2bf(v);
  u16 lo = f2bf(v - bf2f(hi));
  return ((u32)hi << 16) | (u32)lo;
}
// fast tanh
__device__ __forceinline__ float tanh_fast(float x) {
  float xc = fminf(9.0f, fmaxf(-9.0f, x));
  float z = exp2f(xc * 2.8853900817779268f);  // e^{2x}
  return (z - 1.0f) * __builtin_amdgcn_rcpf(z + 1.0f);
}

// ---------- prep: transpose + bf16-split a 1024x1024 weight ----------
__global__ void wsplit(const float* __restrict__ W, u16* __restrict__ Thi, u16* __restrict__ Tlo) {
  __shared__ float tile[32][33];
  const int bx = blockIdx.x * 32;  // c base
  const int by = blockIdx.y * 32;  // k base
  const int tx = threadIdx.x, ty = threadIdx.y;  // (32,8)
#pragma unroll
  for (int r = 0; r < 4; ++r) {
    int ky = ty + 8 * r;
    tile[ky][tx] = W[(size_t)(by + ky) * 1024 + bx + tx];
  }
  __syncthreads();
#pragma unroll
  for (int r = 0; r < 4; ++r) {
    int row = ty + 8 * r;           // c-local
    float v = tile[tx][row];        // = W[by+tx][bx+row]
    u16 hi = f2bf(v);
    u16 lo = f2bf(v - bf2f(hi));
    Thi[(size_t)(bx + row) * 1024 + by + tx] = hi;
    Tlo[(size_t)(bx + row) * 1024 + by + tx] = lo;
  }
}

// ---------- prep: h0 into block-fragment layout (parity 0) + zero flags ----------
// Slab per group g: u64 H[8192]; word for (row,kp) [kp = k/2] at
//   I = (kp>>4)*256 + (kp&3)*64 + ((kp>>2)&3)*16 + row
__global__ void hinit(const float* __restrict__ h0, u64* __restrict__ hb0, int* __restrict__ flags) {
  int i = blockIdx.x * 256 + threadIdx.x;  // 0..32767
  int g = i >> 13, li = i & 8191;
  int Bb = li >> 8, rem = li & 255;
  int j2 = rem >> 6, q = (rem >> 4) & 3, row = rem & 15;
  int kp = Bb * 16 + q * 4 + j2, k = kp * 2;
  int n = g * 16 + row;
  u64 val = (u64)pack_hl(h0[n * 1024 + k]) | ((u64)pack_hl(h0[n * 1024 + k + 1]) << 32);
  __hip_atomic_store(&hb0[i], val, __ATOMIC_RELAXED, SCOPE_AGENT);
  if (i < 64) __hip_atomic_store(&flags[i], 0, __ATOMIC_RELAXED, SCOPE_AGENT);
}

// ---------- phase 1: xw = x @ Wx + b  (bf16x3 MFMA, 128x128 tile, BK=32) ----------
#define LDT 40  // padded LDS row stride (bf16 elems)

__global__ __launch_bounds__(256, 2) void xw_gemm(
    const float* __restrict__ X, const u16* __restrict__ BThi, const u16* __restrict__ BTlo,
    const float* __restrict__ bias, float* __restrict__ out) {
  __shared__ u16 Ah[128 * LDT], Al[128 * LDT], Bh[128 * LDT], Bl[128 * LDT];
  const int tid = threadIdx.x;
  const int lane = tid & 63, wave = tid >> 6;
  const int wm = wave >> 1, wn = wave & 1;
  const int m0 = blockIdx.y * 128, n0 = blockIdx.x * 128;
  const int arow = tid >> 1, afo = (tid & 1) << 4;
  const int bcol = tid >> 1, bko = (tid & 1) << 4;
  const float* Xa = X + (size_t)(m0 + arow) * 1024 + afo;
  const u16* bhp = BThi + (size_t)(n0 + bcol) * 1024 + bko;
  const u16* blp = BTlo + (size_t)(n0 + bcol) * 1024 + bko;

  f32x4 acc[4][4] = {};

  const int aoff = (wm * 64 + (lane & 15)) * LDT + ((lane >> 4) << 3);
  const int boff = (wn * 64 + (lane & 15)) * LDT + ((lane >> 4) << 3);

  for (int k0 = 0; k0 < 1024; k0 += 32) {
    const float4* xp = (const float4*)(Xa + k0);
    float4 f0 = xp[0], f1 = xp[1], f2 = xp[2], f3 = xp[3];
    i32x4 gbh0 = *(const i32x4*)(bhp + k0);
    i32x4 gbh1 = *(const i32x4*)(bhp + k0 + 8);
    i32x4 gbl0 = *(const i32x4*)(blp + k0);
    i32x4 gbl1 = *(const i32x4*)(blp + k0 + 8);
    u32 hw0, hw1, hw2, hw3, hw4, hw5, hw6, hw7;
    u32 lw0, lw1, lw2, lw3, lw4, lw5, lw6, lw7;
    split2(f0.x, f0.y, hw0, lw0); split2(f0.z, f0.w, hw1, lw1);
    split2(f1.x, f1.y, hw2, lw2); split2(f1.z, f1.w, hw3, lw3);
    split2(f2.x, f2.y, hw4, lw4); split2(f2.z, f2.w, hw5, lw5);
    split2(f3.x, f3.y, hw6, lw6); split2(f3.z, f3.w, hw7, lw7);
    __syncthreads();
    *(i32x4*)&Ah[arow * LDT + afo]     = i32x4{(int)hw0, (int)hw1, (int)hw2, (int)hw3};
    *(i32x4*)&Ah[arow * LDT + afo + 8] = i32x4{(int)hw4, (int)hw5, (int)hw6, (int)hw7};
    *(i32x4*)&Al[arow * LDT + afo]     = i32x4{(int)lw0, (int)lw1, (int)lw2, (int)lw3};
    *(i32x4*)&Al[arow * LDT + afo + 8] = i32x4{(int)lw4, (int)lw5, (int)lw6, (int)lw7};
    *(i32x4*)&Bh[bcol * LDT + bko]     = gbh0;
    *(i32x4*)&Bh[bcol * LDT + bko + 8] = gbh1;
    *(i32x4*)&Bl[bcol * LDT + bko]     = gbl0;
    *(i32x4*)&Bl[bcol * LDT + bko + 8] = gbl1;
    __syncthreads();

    bf16x8 a_h[4], a_l[4], b_h[4], b_l[4];
#pragma unroll
    for (int i = 0; i < 4; ++i) {
      a_h[i] = *(const bf16x8*)(Ah + aoff + i * 16 * LDT);
      a_l[i] = *(const bf16x8*)(Al + aoff + i * 16 * LDT);
      b_h[i] = *(const bf16x8*)(Bh + boff + i * 16 * LDT);
      b_l[i] = *(const bf16x8*)(Bl + boff + i * 16 * LDT);
    }
#pragma unroll
    for (int i = 0; i < 4; ++i)
#pragma unroll
      for (int j = 0; j < 4; ++j)
        acc[i][j] = __builtin_amdgcn_mfma_f32_16x16x32_bf16(a_h[i], b_h[j], acc[i][j], 0, 0, 0);
#pragma unroll
    for (int i = 0; i < 4; ++i)
#pragma unroll
      for (int j = 0; j < 4; ++j)
        acc[i][j] = __builtin_amdgcn_mfma_f32_16x16x32_bf16(a_h[i], b_l[j], acc[i][j], 0, 0, 0);
#pragma unroll
    for (int i = 0; i < 4; ++i)
#pragma unroll
      for (int j = 0; j < 4; ++j)
        acc[i][j] = __builtin_amdgcn_mfma_f32_16x16x32_bf16(a_l[i], b_h[j], acc[i][j], 0, 0, 0);
  }
  const int ccol = n0 + wn * 64 + (lane & 15);
  const int crow = m0 + wm * 64 + ((lane >> 4) << 2);
#pragma unroll
  for (int j = 0; j < 4; ++j) {
    float bv = bias[ccol + j * 16];
#pragma unroll
    for (int i = 0; i < 4; ++i)
#pragma unroll
      for (int r = 0; r < 4; ++r)
        out[(size_t)(crow + i * 16 + r) * 1024 + ccol + j * 16] = acc[i][j][r] + bv;
  }
}

// ---------- phase 2: sequential scan ----------
// 64 WGs x 512 threads (8 waves). WG (g,cw): rows [16g,16g+16), cols [64cw,64cw+64).
// Wave w owns K-eighth [w*128,(w+1)*128): B (4 col-tiles x 4 k-steps, hi+lo) pinned
// in 128 VGPRs via inline-asm loads. __launch_bounds__(512,2) caps at 2 waves/EU
// so the allocator is ALLOWED 256 VGPRs (R5's (512) default chose 92 and spilled
// B to scratch -> per-step scratch reloads + 460MB FETCH leak).
#define RST 68  // padded Red row stride (floats) -> kills 4-way write conflicts

__global__ __launch_bounds__(512, 2) void rnn_scan(
    const u16* __restrict__ WThi, const u16* __restrict__ WTlo,
    float* __restrict__ out,
    u64* __restrict__ hb0, u64* __restrict__ hb1,
    int* __restrict__ flags) {
  __shared__ float Red[8][16 * RST];
  const int tid = threadIdx.x;
  const int lane = tid & 63, w = tid >> 6;   // w = K-eighth
  const int cw = blockIdx.x & 15, g = blockIdx.x >> 4;
  const int colL = lane & 15, q = lane >> 4;
  const int fb = g * 16;

  // ---- B -> registers via inline asm (cannot be rematerialized) ----
  i32x4 Bh_[4][4], Bl_[4][4];
#pragma unroll
  for (int ct = 0; ct < 4; ++ct) {
    const u16* bhp = WThi + (size_t)(cw * 64 + ct * 16 + colL) * 1024 + w * 128 + (q << 3);
    const u16* blp = WTlo + (size_t)(cw * 64 + ct * 16 + colL) * 1024 + w * 128 + (q << 3);
#pragma unroll
    for (int t = 0; t < 4; ++t) {
      asm volatile("global_load_dwordx4 %0, %1, off" : "=v"(Bh_[ct][t]) : "v"(bhp + t * 32));
      asm volatile("global_load_dwordx4 %0, %1, off" : "=v"(Bl_[ct][t]) : "v"(blp + t * 32));
    }
  }
  asm volatile("s_waitcnt vmcnt(0)" ::: "memory");
  __builtin_amdgcn_sched_barrier(0);

  const int pwidx = fb + 2 * w + (lane & 1);  // this wave's 2 producers

  // final-phase constants: thread handles outputs (frow, fcc), (frow, fcc+1)
  const int frow = tid >> 5;          // 0..15
  const int fcc = (tid & 31) * 2;     // 0..62
  const int kp = cw * 32 + (tid & 31);
  const size_t pubI = (size_t)(kp >> 4) * 256 + (kp & 3) * 64 + (((kp >> 2) & 3) * 16) + frow;
  const size_t orow = ((size_t)(g * 16 + frow) * 512) * 1024 + cw * 64 + fcc;
  const size_t gbase = (size_t)g * 8192;

  for (int s = 0; s < 512; ++s) {
    // wait for this wave's 2 producers to have published h_s
    while (!__all(__hip_atomic_load(&flags[pwidx], __ATOMIC_RELAXED, SCOPE_AGENT) >= s))
      __builtin_amdgcn_s_sleep(1);
    asm volatile("" ::: "memory");

    // dense uncached pull of this wave's slab eighth: 16 u64 loads, 512B/instr
    const u64* src = ((s & 1) ? hb1 : hb0) + gbase + (size_t)w * 1024 + lane;
    u64 hw_[16];
#pragma unroll
    for (int t = 0; t < 4; ++t)
#pragma unroll
      for (int j2 = 0; j2 < 4; ++j2)
        hw_[t * 4 + j2] = __hip_atomic_load(src + t * 256 + j2 * 64, __ATOMIC_RELAXED, SCOPE_AGENT);

    // xw prefetch (cached) — overlaps the pull latency
    const size_t oidx = orow + (size_t)s * 1024;
    float2 xwv = *(const float2*)&out[oidx];

    f32x4 acc[4] = {};
#pragma unroll
    for (int t = 0; t < 4; ++t) {
      u64 w0 = hw_[t * 4 + 0], w1 = hw_[t * 4 + 1], w2 = hw_[t * 4 + 2], w3 = hw_[t * 4 + 3];
      i32x4 ahv, alv;
      ahv[0] = (int)__builtin_amdgcn_perm((u32)(w0 >> 32), (u32)w0, 0x07060302u);
      alv[0] = (int)__builtin_amdgcn_perm((u32)(w0 >> 32), (u32)w0, 0x05040100u);
      ahv[1] = (int)__builtin_amdgcn_perm((u32)(w1 >> 32), (u32)w1, 0x07060302u);
      alv[1] = (int)__builtin_amdgcn_perm((u32)(w1 >> 32), (u32)w1, 0x05040100u);
      ahv[2] = (int)__builtin_amdgcn_perm((u32)(w2 >> 32), (u32)w2, 0x07060302u);
      alv[2] = (int)__builtin_amdgcn_perm((u32)(w2 >> 32), (u32)w2, 0x05040100u);
      ahv[3] = (int)__builtin_amdgcn_perm((u32)(w3 >> 32), (u32)w3, 0x07060302u);
      alv[3] = (int)__builtin_amdgcn_perm((u32)(w3 >> 32), (u32)w3, 0x05040100u);
      bf16x8 ah = __builtin_bit_cast(bf16x8, ahv);
      bf16x8 al = __builtin_bit_cast(bf16x8, alv);
#pragma unroll
      for (int ct = 0; ct < 4; ++ct) {
        acc[ct] = __builtin_amdgcn_mfma_f32_16x16x32_bf16(al, __builtin_bit_cast(bf16x8, Bh_[ct][t]), acc[ct], 0, 0, 0);
        acc[ct] = __builtin_amdgcn_mfma_f32_16x16x32_bf16(ah, __builtin_bit_cast(bf16x8, Bl_[ct][t]), acc[ct], 0, 0, 0);
        acc[ct] = __builtin_amdgcn_mfma_f32_16x16x32_bf16(ah, __builtin_bit_cast(bf16x8, Bh_[ct][t]), acc[ct], 0, 0, 0);
      }
    }

    // partials -> LDS  (row_local = q*4+r, col_local = ct*16+colL), padded stride
#pragma unroll
    for (int ct = 0; ct < 4; ++ct)
#pragma unroll
      for (int r = 0; r < 4; ++r)
        Red[w][(q * 4 + r) * RST + ct * 16 + colL] = acc[ct][r];
    __syncthreads();

    // final: each thread reduces 8 partials for its 2 outputs
    float s0 = xwv.x, s1 = xwv.y;
#pragma unroll
    for (int ww = 0; ww < 8; ++ww) {
      float2 pr = *(const float2*)&Red[ww][frow * RST + fcc];
      s0 += pr.x; s1 += pr.y;
    }
    float h0v = tanh_fast(s0), h1v = tanh_fast(s1);
    u64* ob = ((s & 1) ? hb0 : hb1) + gbase;
    u64 val = (u64)pack_hl(h0v) | ((u64)pack_hl(h1v) << 32);
    __hip_atomic_store(ob + pubI, val, __ATOMIC_RELAXED, SCOPE_AGENT);
    *(float2*)&out[oidx] = make_float2(h0v, h1v);

    // release: drain publish stores, barrier (all waves drained + Red reads done),
    // then one flag for the WG
    asm volatile("s_waitcnt vmcnt(0)" ::: "memory");
    __syncthreads();
    if (tid == 0)
      __hip_atomic_store(&flags[fb + cw], s + 1, __ATOMIC_RELAXED, SCOPE_AGENT);
  }
}

// ---------- launch ----------
extern "C" void kernel_launch(void* const* d_in, const int* in_sizes, int n_in,
                              void* d_out, int out_size, void* d_ws, size_t ws_size,
                              hipStream_t stream) {
  const float* x    = (const float*)d_in[0];
  const float* h0   = (const float*)d_in[1];
  const float* Wx   = (const float*)d_in[2];
  const float* Wh   = (const float*)d_in[3];
  const float* bias = (const float*)d_in[4];
  float* out = (float*)d_out;
  char* ws = (char*)d_ws;

  const size_t MB2 = (size_t)1 << 21;
  u16* WxThi = (u16*)(ws);
  u16* WxTlo = (u16*)(ws + MB2);
  u16* WhThi = (u16*)(ws + 2 * MB2);
  u16* WhTlo = (u16*)(ws + 3 * MB2);
  u64* hb0   = (u64*)(ws + 4 * MB2);
  u64* hb1   = (u64*)(ws + 4 * MB2 + 32768 * sizeof(u64));
  int* flags = (int*)(ws + 4 * MB2 + 2 * 32768 * sizeof(u64));

  wsplit<<<dim3(32, 32), dim3(32, 8), 0, stream>>>(Wx, WxThi, WxTlo);
  wsplit<<<dim3(32, 32), dim3(32, 8), 0, stream>>>(Wh, WhThi, WhTlo);
  hinit<<<128, 256, 0, stream>>>(h0, hb0, flags);
  xw_gemm<<<dim3(8, 256), 256, 0, stream>>>(x, WxThi, WxTlo, bias, out);
  rnn_scan<<<64, 512, 0, stream>>>(WhThi, WhTlo, out, hb0, hb1, flags);
}

// Round 8
// 1986.178 us; speedup vs baseline: 3.0192x; 1.0884x over previous
//
#include <hip/hip_runtime.h>
#include <hip/hip_bf16.h>
#include <stdint.h>
#include <stddef.h>

typedef short bf16x8 __attribute__((ext_vector_type(8)));
typedef float f32x4 __attribute__((ext_vector_type(4)));
typedef int i32x4 __attribute__((ext_vector_type(4)));
typedef unsigned short u16;
typedef unsigned int u32;
typedef unsigned long long u64;

#define SCOPE_AGENT __HIP_MEMORY_SCOPE_AGENT
#define SENT 0xFFFFFFFFFFFFFFFFull

// ---------- helpers: fp32 -> bf16 (RNE) split ----------
__device__ __forceinline__ u16 f2bf(float x) {
  u32 u = __builtin_bit_cast(u32, x);
  u32 r = (u + 0x7fffu + ((u >> 16) & 1u)) >> 16;
  return (u16)r;
}
__device__ __forceinline__ float bf2f(u16 h) {
  u32 u = ((u32)h) << 16;
  return __builtin_bit_cast(float, u);
}
__device__ __forceinline__ void split2(float a, float b, u32& hw, u32& lw) {
  u16 ha = f2bf(a), hb = f2bf(b);
  float ra = a - bf2f(ha), rb = b - bf2f(hb);
  hw = (u32)ha | ((u32)hb << 16);
  lw = (u32)f2bf(ra) | ((u32)f2bf(rb) << 16);
}
// pack h value as (bf16_hi << 16) | bf16_lo  (hi is a finite tanh output ->
// never 0xFFFF, so 0xFFFFFFFF can be used as a sentinel half-word)
__device__ __forceinline__ u32 pack_hl(float v) {
  u16 hi = f2bf(v);
  u16 lo = f2bf(v - bf2f(hi));
  return ((u32)hi << 16) | (u32)lo;
}
__device__ __forceinline__ float tanh_fast(float x) {
  float xc = fminf(9.0f, fmaxf(-9.0f, x));
  float z = exp2f(xc * 2.8853900817779268f);  // e^{2x}
  return (z - 1.0f) * __builtin_amdgcn_rcpf(z + 1.0f);
}

// ---------- prep: transpose + bf16-split a 1024x1024 weight ----------
__global__ void wsplit(const float* __restrict__ W, u16* __restrict__ Thi, u16* __restrict__ Tlo) {
  __shared__ float tile[32][33];
  const int bx = blockIdx.x * 32;  // c base
  const int by = blockIdx.y * 32;  // k base
  const int tx = threadIdx.x, ty = threadIdx.y;  // (32,8)
#pragma unroll
  for (int r = 0; r < 4; ++r) {
    int ky = ty + 8 * r;
    tile[ky][tx] = W[(size_t)(by + ky) * 1024 + bx + tx];
  }
  __syncthreads();
#pragma unroll
  for (int r = 0; r < 4; ++r) {
    int row = ty + 8 * r;           // c-local
    float v = tile[tx][row];        // = W[by+tx][bx+row]
    u16 hi = f2bf(v);
    u16 lo = f2bf(v - bf2f(hi));
    Thi[(size_t)(bx + row) * 1024 + by + tx] = hi;
    Tlo[(size_t)(bx + row) * 1024 + by + tx] = lo;
  }
}

// ---------- prep: ring init ----------
// ring = 4 slots x (4 groups x 8192 u64). Slot 0 <- h0 in block-fragment
// layout: word (row,kp) [kp=k/2] at I = (kp>>4)*256 + (kp&3)*64 +
// ((kp>>2)&3)*16 + row. Slots 1..3 <- sentinel. Re-done every launch
// (deterministic across graph replays).
__global__ void hinit(const float* __restrict__ h0, u64* __restrict__ ring) {
  int i = blockIdx.x * 256 + threadIdx.x;  // 0..131071
  int slot = i >> 15, li = i & 32767;
  if (slot == 0) {
    int g = li >> 13, I = li & 8191;
    int Bb = I >> 8, rem = I & 255;
    int j2 = rem >> 6, q = (rem >> 4) & 3, row = rem & 15;
    int kp = Bb * 16 + q * 4 + j2, k = kp * 2;
    int n = g * 16 + row;
    u64 val = (u64)pack_hl(h0[n * 1024 + k]) | ((u64)pack_hl(h0[n * 1024 + k + 1]) << 32);
    __hip_atomic_store(&ring[i], val, __ATOMIC_RELAXED, SCOPE_AGENT);
  } else {
    __hip_atomic_store(&ring[i], SENT, __ATOMIC_RELAXED, SCOPE_AGENT);
  }
}

// ---------- phase 1: xw = x @ Wx + b  (bf16x3 MFMA, 128x128 tile, BK=32) ----------
#define LDT 40  // padded LDS row stride (bf16 elems)

__global__ __launch_bounds__(256, 2) void xw_gemm(
    const float* __restrict__ X, const u16* __restrict__ BThi, const u16* __restrict__ BTlo,
    const float* __restrict__ bias, float* __restrict__ out) {
  __shared__ u16 Ah[128 * LDT], Al[128 * LDT], Bh[128 * LDT], Bl[128 * LDT];
  const int tid = threadIdx.x;
  const int lane = tid & 63, wave = tid >> 6;
  const int wm = wave >> 1, wn = wave & 1;
  const int m0 = blockIdx.y * 128, n0 = blockIdx.x * 128;
  const int arow = tid >> 1, afo = (tid & 1) << 4;
  const int bcol = tid >> 1, bko = (tid & 1) << 4;
  const float* Xa = X + (size_t)(m0 + arow) * 1024 + afo;
  const u16* bhp = BThi + (size_t)(n0 + bcol) * 1024 + bko;
  const u16* blp = BTlo + (size_t)(n0 + bcol) * 1024 + bko;

  f32x4 acc[4][4] = {};

  const int aoff = (wm * 64 + (lane & 15)) * LDT + ((lane >> 4) << 3);
  const int boff = (wn * 64 + (lane & 15)) * LDT + ((lane >> 4) << 3);

  for (int k0 = 0; k0 < 1024; k0 += 32) {
    const float4* xp = (const float4*)(Xa + k0);
    float4 f0 = xp[0], f1 = xp[1], f2 = xp[2], f3 = xp[3];
    i32x4 gbh0 = *(const i32x4*)(bhp + k0);
    i32x4 gbh1 = *(const i32x4*)(bhp + k0 + 8);
    i32x4 gbl0 = *(const i32x4*)(blp + k0);
    i32x4 gbl1 = *(const i32x4*)(blp + k0 + 8);
    u32 hw0, hw1, hw2, hw3, hw4, hw5, hw6, hw7;
    u32 lw0, lw1, lw2, lw3, lw4, lw5, lw6, lw7;
    split2(f0.x, f0.y, hw0, lw0); split2(f0.z, f0.w, hw1, lw1);
    split2(f1.x, f1.y, hw2, lw2); split2(f1.z, f1.w, hw3, lw3);
    split2(f2.x, f2.y, hw4, lw4); split2(f2.z, f2.w, hw5, lw5);
    split2(f3.x, f3.y, hw6, lw6); split2(f3.z, f3.w, hw7, lw7);
    __syncthreads();
    *(i32x4*)&Ah[arow * LDT + afo]     = i32x4{(int)hw0, (int)hw1, (int)hw2, (int)hw3};
    *(i32x4*)&Ah[arow * LDT + afo + 8] = i32x4{(int)hw4, (int)hw5, (int)hw6, (int)hw7};
    *(i32x4*)&Al[arow * LDT + afo]     = i32x4{(int)lw0, (int)lw1, (int)lw2, (int)lw3};
    *(i32x4*)&Al[arow * LDT + afo + 8] = i32x4{(int)lw4, (int)lw5, (int)lw6, (int)lw7};
    *(i32x4*)&Bh[bcol * LDT + bko]     = gbh0;
    *(i32x4*)&Bh[bcol * LDT + bko + 8] = gbh1;
    *(i32x4*)&Bl[bcol * LDT + bko]     = gbl0;
    *(i32x4*)&Bl[bcol * LDT + bko + 8] = gbl1;
    __syncthreads();

    bf16x8 a_h[4], a_l[4], b_h[4], b_l[4];
#pragma unroll
    for (int i = 0; i < 4; ++i) {
      a_h[i] = *(const bf16x8*)(Ah + aoff + i * 16 * LDT);
      a_l[i] = *(const bf16x8*)(Al + aoff + i * 16 * LDT);
      b_h[i] = *(const bf16x8*)(Bh + boff + i * 16 * LDT);
      b_l[i] = *(const bf16x8*)(Bl + boff + i * 16 * LDT);
    }
#pragma unroll
    for (int i = 0; i < 4; ++i)
#pragma unroll
      for (int j = 0; j < 4; ++j)
        acc[i][j] = __builtin_amdgcn_mfma_f32_16x16x32_bf16(a_h[i], b_h[j], acc[i][j], 0, 0, 0);
#pragma unroll
    for (int i = 0; i < 4; ++i)
#pragma unroll
      for (int j = 0; j < 4; ++j)
        acc[i][j] = __builtin_amdgcn_mfma_f32_16x16x32_bf16(a_h[i], b_l[j], acc[i][j], 0, 0, 0);
#pragma unroll
    for (int i = 0; i < 4; ++i)
#pragma unroll
      for (int j = 0; j < 4; ++j)
        acc[i][j] = __builtin_amdgcn_mfma_f32_16x16x32_bf16(a_l[i], b_h[j], acc[i][j], 0, 0, 0);
  }
  const int ccol = n0 + wn * 64 + (lane & 15);
  const int crow = m0 + wm * 64 + ((lane >> 4) << 2);
#pragma unroll
  for (int j = 0; j < 4; ++j) {
    float bv = bias[ccol + j * 16];
#pragma unroll
    for (int i = 0; i < 4; ++i)
#pragma unroll
      for (int r = 0; r < 4; ++r)
        out[(size_t)(crow + i * 16 + r) * 1024 + ccol + j * 16] = acc[i][j][r] + bv;
  }
}

// ---------- phase 2: sequential scan, flagless ring-4 data polling ----------
// R6 geometry (proven): 64 WGs x 512 thr; WG (g,cw): rows [16g,16g+16),
// cols [64cw,64cw+64); wave w owns K-eighth, B pinned via inline-asm loads.
// Sync: consumers poll the DATA words of ring[s&3] until != sentinel (poll IS
// the pull). Producers publish into ring[(s+1)&3] fire-and-forget, then
// sentinel their own words in ring[(s-1)&3]. Clear-issue causally follows all
// step-(s-1) readers (a WG publishes only after pulling all 16 roles' words);
// clear stores are drained by the NEXT step's pull-vmcnt before that publish,
// so they are globally ordered 2 publish-hops before the slot is re-polled
// (this is why depth 4, not 3). One barrier/step; Red is parity-buffered.
#define RST 68  // padded Red row stride (floats)

__global__ __launch_bounds__(512, 2) void rnn_scan(
    const u16* __restrict__ WThi, const u16* __restrict__ WTlo,
    float* __restrict__ out, u64* __restrict__ ring) {
  __shared__ float Red[2][8][16 * RST];
  const int tid = threadIdx.x;
  const int lane = tid & 63, w = tid >> 6;   // w = K-eighth
  const int cw = blockIdx.x & 15, g = blockIdx.x >> 4;
  const int colL = lane & 15, q = lane >> 4;

  // ---- B -> registers/AGPRs via inline asm (never rematerialized) ----
  i32x4 Bh_[4][4], Bl_[4][4];
#pragma unroll
  for (int ct = 0; ct < 4; ++ct) {
    const u16* bhp = WThi + (size_t)(cw * 64 + ct * 16 + colL) * 1024 + w * 128 + (q << 3);
    const u16* blp = WTlo + (size_t)(cw * 64 + ct * 16 + colL) * 1024 + w * 128 + (q << 3);
#pragma unroll
    for (int t = 0; t < 4; ++t) {
      asm volatile("global_load_dwordx4 %0, %1, off" : "=v"(Bh_[ct][t]) : "v"(bhp + t * 32));
      asm volatile("global_load_dwordx4 %0, %1, off" : "=v"(Bl_[ct][t]) : "v"(blp + t * 32));
    }
  }
  asm volatile("s_waitcnt vmcnt(0)" ::: "memory");
  __builtin_amdgcn_sched_barrier(0);

  // final-phase constants: thread handles outputs (frow, fcc), (frow, fcc+1)
  const int frow = tid >> 5;          // 0..15
  const int fcc = (tid & 31) * 2;     // 0..62
  const int kp = cw * 32 + (tid & 31);
  const size_t pubI = (size_t)(kp >> 4) * 256 + (kp & 3) * 64 + (((kp >> 2) & 3) * 16) + frow;
  const size_t orow = ((size_t)(g * 16 + frow) * 512) * 1024 + cw * 64 + fcc;
  const size_t gslab = (size_t)g * 8192;
  const size_t srcoff = gslab + (size_t)w * 1024 + lane;

  for (int s = 0; s < 512; ++s) {
    // xw prefetch (cached, WG-private) -- issue before the poll
    const size_t oidx = orow + (size_t)s * 1024;
    float2 xwv = *(const float2*)&out[oidx];
    asm volatile("" : "+v"(xwv.x), "+v"(xwv.y));

    // poll-pull: this wave's 16 slab words; sentinel -> not yet published
    const u64* src = ring + (size_t)(s & 3) * 32768 + srcoff;
    u64 hv[16];
    {
      int it = 0;
      bool ok;
      do {
#pragma unroll
        for (int t = 0; t < 4; ++t)
#pragma unroll
          for (int j2 = 0; j2 < 4; ++j2)
            hv[t * 4 + j2] =
                __hip_atomic_load(src + t * 256 + j2 * 64, __ATOMIC_RELAXED, SCOPE_AGENT);
        bool d = true;
#pragma unroll
        for (int i = 0; i < 16; ++i) d = d && (hv[i] != SENT);
        ok = __all(d);
      } while (!ok && ++it < (1 << 16));
    }

    f32x4 acc[4] = {};
#pragma unroll
    for (int t = 0; t < 4; ++t) {
      u64 w0 = hv[t * 4 + 0], w1 = hv[t * 4 + 1], w2 = hv[t * 4 + 2], w3 = hv[t * 4 + 3];
      i32x4 ahv, alv;
      ahv[0] = (int)__builtin_amdgcn_perm((u32)(w0 >> 32), (u32)w0, 0x07060302u);
      alv[0] = (int)__builtin_amdgcn_perm((u32)(w0 >> 32), (u32)w0, 0x05040100u);
      ahv[1] = (int)__builtin_amdgcn_perm((u32)(w1 >> 32), (u32)w1, 0x07060302u);
      alv[1] = (int)__builtin_amdgcn_perm((u32)(w1 >> 32), (u32)w1, 0x05040100u);
      ahv[2] = (int)__builtin_amdgcn_perm((u32)(w2 >> 32), (u32)w2, 0x07060302u);
      alv[2] = (int)__builtin_amdgcn_perm((u32)(w2 >> 32), (u32)w2, 0x05040100u);
      ahv[3] = (int)__builtin_amdgcn_perm((u32)(w3 >> 32), (u32)w3, 0x07060302u);
      alv[3] = (int)__builtin_amdgcn_perm((u32)(w3 >> 32), (u32)w3, 0x05040100u);
      bf16x8 ah = __builtin_bit_cast(bf16x8, ahv);
      bf16x8 al = __builtin_bit_cast(bf16x8, alv);
#pragma unroll
      for (int ct = 0; ct < 4; ++ct) {
        acc[ct] = __builtin_amdgcn_mfma_f32_16x16x32_bf16(al, __builtin_bit_cast(bf16x8, Bh_[ct][t]), acc[ct], 0, 0, 0);
        acc[ct] = __builtin_amdgcn_mfma_f32_16x16x32_bf16(ah, __builtin_bit_cast(bf16x8, Bl_[ct][t]), acc[ct], 0, 0, 0);
        acc[ct] = __builtin_amdgcn_mfma_f32_16x16x32_bf16(ah, __builtin_bit_cast(bf16x8, Bh_[ct][t]), acc[ct], 0, 0, 0);
      }
    }

    // partials -> LDS (parity-buffered; row_local = q*4+r, col_local = ct*16+colL)
#pragma unroll
    for (int ct = 0; ct < 4; ++ct)
#pragma unroll
      for (int r = 0; r < 4; ++r)
        Red[s & 1][w][(q * 4 + r) * RST + ct * 16 + colL] = acc[ct][r];
    __syncthreads();

    // final: reduce 8 K-partials for this thread's 2 outputs
    float s0 = xwv.x, s1 = xwv.y;
#pragma unroll
    for (int ww = 0; ww < 8; ++ww) {
      float2 pr = *(const float2*)&Red[s & 1][ww][frow * RST + fcc];
      s0 += pr.x; s1 += pr.y;
    }
    float h0v = tanh_fast(s0), h1v = tanh_fast(s1);

    // publish h_{s+1} into ring[(s+1)&3] (fire-and-forget, data IS the flag)
    u64 val = (u64)pack_hl(h0v) | ((u64)pack_hl(h1v) << 32);
    __hip_atomic_store(ring + (size_t)((s + 1) & 3) * 32768 + gslab + pubI, val,
                       __ATOMIC_RELAXED, SCOPE_AGENT);
    // sentinel my word in the slot read last step; drained by next pull-vmcnt
    if (s > 0)
      __hip_atomic_store(ring + (size_t)((s - 1) & 3) * 32768 + gslab + pubI, SENT,
                         __ATOMIC_RELAXED, SCOPE_AGENT);
    // d_out store off the critical path (cached, WG-private)
    *(float2*)&out[oidx] = make_float2(h0v, h1v);
  }
}

// ---------- launch ----------
extern "C" void kernel_launch(void* const* d_in, const int* in_sizes, int n_in,
                              void* d_out, int out_size, void* d_ws, size_t ws_size,
                              hipStream_t stream) {
  const float* x    = (const float*)d_in[0];
  const float* h0   = (const float*)d_in[1];
  const float* Wx   = (const float*)d_in[2];
  const float* Wh   = (const float*)d_in[3];
  const float* bias = (const float*)d_in[4];
  float* out = (float*)d_out;
  char* ws = (char*)d_ws;

  const size_t MB2 = (size_t)1 << 21;
  u16* WxThi = (u16*)(ws);
  u16* WxTlo = (u16*)(ws + MB2);
  u16* WhThi = (u16*)(ws + 2 * MB2);
  u16* WhTlo = (u16*)(ws + 3 * MB2);
  u64* ring  = (u64*)(ws + 4 * MB2);  // 4 slots x 32768 u64 = 1 MB

  wsplit<<<dim3(32, 32), dim3(32, 8), 0, stream>>>(Wx, WxThi, WxTlo);
  wsplit<<<dim3(32, 32), dim3(32, 8), 0, stream>>>(Wh, WhThi, WhTlo);
  hinit<<<512, 256, 0, stream>>>(h0, ring);
  xw_gemm<<<dim3(8, 256), 256, 0, stream>>>(x, WxThi, WxTlo, bias, out);
  rnn_scan<<<64, 512, 0, stream>>>(WhThi, WhTlo, out, ring);
}

// Round 9
// 1869.475 us; speedup vs baseline: 3.2077x; 1.0624x over previous
//
#include <hip/hip_runtime.h>
#include <hip/hip_bf16.h>
#include <stdint.h>
#include <stddef.h>

typedef short bf16x8 __attribute__((ext_vector_type(8)));
typedef float f32x4 __attribute__((ext_vector_type(4)));
typedef int i32x4 __attribute__((ext_vector_type(4)));
typedef unsigned short u16;
typedef unsigned int u32;
typedef unsigned long long u64;

#define SCOPE_AGENT __HIP_MEMORY_SCOPE_AGENT
#define SENT 0xFFFFFFFFFFFFFFFFull

// ---------- helpers: fp32 -> bf16 (RNE) split ----------
__device__ __forceinline__ u16 f2bf(float x) {
  u32 u = __builtin_bit_cast(u32, x);
  u32 r = (u + 0x7fffu + ((u >> 16) & 1u)) >> 16;
  return (u16)r;
}
__device__ __forceinline__ float bf2f(u16 h) {
  u32 u = ((u32)h) << 16;
  return __builtin_bit_cast(float, u);
}
__device__ __forceinline__ void split2(float a, float b, u32& hw, u32& lw) {
  u16 ha = f2bf(a), hb = f2bf(b);
  float ra = a - bf2f(ha), rb = b - bf2f(hb);
  hw = (u32)ha | ((u32)hb << 16);
  lw = (u32)f2bf(ra) | ((u32)f2bf(rb) << 16);
}
// pack h value as (bf16_hi << 16) | bf16_lo  (hi is a finite tanh output ->
// never 0xFFFF, so the all-ones word can serve as a sentinel)
__device__ __forceinline__ u32 pack_hl(float v) {
  u16 hi = f2bf(v);
  u16 lo = f2bf(v - bf2f(hi));
  return ((u32)hi << 16) | (u32)lo;
}
__device__ __forceinline__ float tanh_fast(float x) {
  float xc = fminf(9.0f, fmaxf(-9.0f, x));
  float z = exp2f(xc * 2.8853900817779268f);  // e^{2x}
  return (z - 1.0f) * __builtin_amdgcn_rcpf(z + 1.0f);
}

// ---------- prep: transpose + bf16-split a 1024x1024 weight ----------
__global__ void wsplit(const float* __restrict__ W, u16* __restrict__ Thi, u16* __restrict__ Tlo) {
  __shared__ float tile[32][33];
  const int bx = blockIdx.x * 32;  // c base
  const int by = blockIdx.y * 32;  // k base
  const int tx = threadIdx.x, ty = threadIdx.y;  // (32,8)
#pragma unroll
  for (int r = 0; r < 4; ++r) {
    int ky = ty + 8 * r;
    tile[ky][tx] = W[(size_t)(by + ky) * 1024 + bx + tx];
  }
  __syncthreads();
#pragma unroll
  for (int r = 0; r < 4; ++r) {
    int row = ty + 8 * r;           // c-local
    float v = tile[tx][row];        // = W[by+tx][bx+row]
    u16 hi = f2bf(v);
    u16 lo = f2bf(v - bf2f(hi));
    Thi[(size_t)(bx + row) * 1024 + by + tx] = hi;
    Tlo[(size_t)(bx + row) * 1024 + by + tx] = lo;
  }
}

// ---------- prep: ring init ----------
// ring = 4 slots x (4 groups x 8192 u64). Slot 0 <- h0 in block-fragment
// layout: word (row,kp) [kp=k/2] at I = (kp>>4)*256 + (kp&3)*64 +
// ((kp>>2)&3)*16 + row. Slots 1..3 <- sentinel.
__global__ void hinit(const float* __restrict__ h0, u64* __restrict__ ring) {
  int i = blockIdx.x * 256 + threadIdx.x;  // 0..131071
  int slot = i >> 15, li = i & 32767;
  if (slot == 0) {
    int g = li >> 13, I = li & 8191;
    int Bb = I >> 8, rem = I & 255;
    int j2 = rem >> 6, q = (rem >> 4) & 3, row = rem & 15;
    int kp = Bb * 16 + q * 4 + j2, k = kp * 2;
    int n = g * 16 + row;
    u64 val = (u64)pack_hl(h0[n * 1024 + k]) | ((u64)pack_hl(h0[n * 1024 + k + 1]) << 32);
    __hip_atomic_store(&ring[i], val, __ATOMIC_RELAXED, SCOPE_AGENT);
  } else {
    __hip_atomic_store(&ring[i], SENT, __ATOMIC_RELAXED, SCOPE_AGENT);
  }
}

// ---------- phase 1: xw = x @ Wx + b  (bf16x3 MFMA, 128x128 tile, BK=32) ----------
#define LDT 40  // padded LDS row stride (bf16 elems)

__global__ __launch_bounds__(256, 2) void xw_gemm(
    const float* __restrict__ X, const u16* __restrict__ BThi, const u16* __restrict__ BTlo,
    const float* __restrict__ bias, float* __restrict__ out) {
  __shared__ u16 Ah[128 * LDT], Al[128 * LDT], Bh[128 * LDT], Bl[128 * LDT];
  const int tid = threadIdx.x;
  const int lane = tid & 63, wave = tid >> 6;
  const int wm = wave >> 1, wn = wave & 1;
  const int m0 = blockIdx.y * 128, n0 = blockIdx.x * 128;
  const int arow = tid >> 1, afo = (tid & 1) << 4;
  const int bcol = tid >> 1, bko = (tid & 1) << 4;
  const float* Xa = X + (size_t)(m0 + arow) * 1024 + afo;
  const u16* bhp = BThi + (size_t)(n0 + bcol) * 1024 + bko;
  const u16* blp = BTlo + (size_t)(n0 + bcol) * 1024 + bko;

  f32x4 acc[4][4] = {};

  const int aoff = (wm * 64 + (lane & 15)) * LDT + ((lane >> 4) << 3);
  const int boff = (wn * 64 + (lane & 15)) * LDT + ((lane >> 4) << 3);

  for (int k0 = 0; k0 < 1024; k0 += 32) {
    const float4* xp = (const float4*)(Xa + k0);
    float4 f0 = xp[0], f1 = xp[1], f2 = xp[2], f3 = xp[3];
    i32x4 gbh0 = *(const i32x4*)(bhp + k0);
    i32x4 gbh1 = *(const i32x4*)(bhp + k0 + 8);
    i32x4 gbl0 = *(const i32x4*)(blp + k0);
    i32x4 gbl1 = *(const i32x4*)(blp + k0 + 8);
    u32 hw0, hw1, hw2, hw3, hw4, hw5, hw6, hw7;
    u32 lw0, lw1, lw2, lw3, lw4, lw5, lw6, lw7;
    split2(f0.x, f0.y, hw0, lw0); split2(f0.z, f0.w, hw1, lw1);
    split2(f1.x, f1.y, hw2, lw2); split2(f1.z, f1.w, hw3, lw3);
    split2(f2.x, f2.y, hw4, lw4); split2(f2.z, f2.w, hw5, lw5);
    split2(f3.x, f3.y, hw6, lw6); split2(f3.z, f3.w, hw7, lw7);
    __syncthreads();
    *(i32x4*)&Ah[arow * LDT + afo]     = i32x4{(int)hw0, (int)hw1, (int)hw2, (int)hw3};
    *(i32x4*)&Ah[arow * LDT + afo + 8] = i32x4{(int)hw4, (int)hw5, (int)hw6, (int)hw7};
    *(i32x4*)&Al[arow * LDT + afo]     = i32x4{(int)lw0, (int)lw1, (int)lw2, (int)lw3};
    *(i32x4*)&Al[arow * LDT + afo + 8] = i32x4{(int)lw4, (int)lw5, (int)lw6, (int)lw7};
    *(i32x4*)&Bh[bcol * LDT + bko]     = gbh0;
    *(i32x4*)&Bh[bcol * LDT + bko + 8] = gbh1;
    *(i32x4*)&Bl[bcol * LDT + bko]     = gbl0;
    *(i32x4*)&Bl[bcol * LDT + bko + 8] = gbl1;
    __syncthreads();

    bf16x8 a_h[4], a_l[4], b_h[4], b_l[4];
#pragma unroll
    for (int i = 0; i < 4; ++i) {
      a_h[i] = *(const bf16x8*)(Ah + aoff + i * 16 * LDT);
      a_l[i] = *(const bf16x8*)(Al + aoff + i * 16 * LDT);
      b_h[i] = *(const bf16x8*)(Bh + boff + i * 16 * LDT);
      b_l[i] = *(const bf16x8*)(Bl + boff + i * 16 * LDT);
    }
#pragma unroll
    for (int i = 0; i < 4; ++i)
#pragma unroll
      for (int j = 0; j < 4; ++j)
        acc[i][j] = __builtin_amdgcn_mfma_f32_16x16x32_bf16(a_h[i], b_h[j], acc[i][j], 0, 0, 0);
#pragma unroll
    for (int i = 0; i < 4; ++i)
#pragma unroll
      for (int j = 0; j < 4; ++j)
        acc[i][j] = __builtin_amdgcn_mfma_f32_16x16x32_bf16(a_h[i], b_l[j], acc[i][j], 0, 0, 0);
#pragma unroll
    for (int i = 0; i < 4; ++i)
#pragma unroll
      for (int j = 0; j < 4; ++j)
        acc[i][j] = __builtin_amdgcn_mfma_f32_16x16x32_bf16(a_l[i], b_h[j], acc[i][j], 0, 0, 0);
  }
  const int ccol = n0 + wn * 64 + (lane & 15);
  const int crow = m0 + wm * 64 + ((lane >> 4) << 2);
#pragma unroll
  for (int j = 0; j < 4; ++j) {
    float bv = bias[ccol + j * 16];
#pragma unroll
    for (int i = 0; i < 4; ++i)
#pragma unroll
      for (int r = 0; r < 4; ++r)
        out[(size_t)(crow + i * 16 + r) * 1024 + ccol + j * 16] = acc[i][j][r] + bv;
  }
}

// ---------- phase 2: sequential scan, flagless ring-4, dense publish ----------
// R8 protocol (proven) with two changes:
//  (1) final-phase thread mapping re-derived so thread tid publishes slab word
//      I = cw*512 + tid  -> each wave's publish/sentinel is ONE dense 512B
//      burst (R8's scattered 8B stores caused ~250MB write amplification and
//      slow visibility). Inversion of the slab layout gives this thread the
//      outputs (row = tid&15, k = 2*kp, 2*kp+1) with
//      kp = (2cw + (tid>>8))*16 + ((rem>>4)&3)*4 + (rem>>6), rem = tid&255.
//  (2) poll re-loads only still-sentinel words (exec-masked) instead of
//      re-pulling all 16 -> ~8x less re-poll traffic on the uncached path.
#define RST 68  // padded Red row stride (floats)

__global__ __launch_bounds__(512, 2) void rnn_scan(
    const u16* __restrict__ WThi, const u16* __restrict__ WTlo,
    float* __restrict__ out, u64* __restrict__ ring) {
  __shared__ float Red[2][8][16 * RST];
  const int tid = threadIdx.x;
  const int lane = tid & 63, w = tid >> 6;   // w = K-eighth
  const int cw = blockIdx.x & 15, g = blockIdx.x >> 4;
  const int colL = lane & 15, q = lane >> 4;

  // ---- B -> registers/AGPRs via inline asm (never rematerialized) ----
  i32x4 Bh_[4][4], Bl_[4][4];
#pragma unroll
  for (int ct = 0; ct < 4; ++ct) {
    const u16* bhp = WThi + (size_t)(cw * 64 + ct * 16 + colL) * 1024 + w * 128 + (q << 3);
    const u16* blp = WTlo + (size_t)(cw * 64 + ct * 16 + colL) * 1024 + w * 128 + (q << 3);
#pragma unroll
    for (int t = 0; t < 4; ++t) {
      asm volatile("global_load_dwordx4 %0, %1, off" : "=v"(Bh_[ct][t]) : "v"(bhp + t * 32));
      asm volatile("global_load_dwordx4 %0, %1, off" : "=v"(Bl_[ct][t]) : "v"(blp + t * 32));
    }
  }
  asm volatile("s_waitcnt vmcnt(0)" ::: "memory");
  __builtin_amdgcn_sched_barrier(0);

  // final-phase constants (dense-publish mapping, see header comment)
  const int rem = tid & 255;
  const int frow = tid & 15;                                    // batch-row local
  const int kp = (2 * cw + (tid >> 8)) * 16 + ((rem >> 4) & 3) * 4 + (rem >> 6);
  const int colL2 = 2 * (kp - cw * 32);                         // 0..62 local col
  const size_t pubI = (size_t)cw * 512 + tid;                   // DENSE
  const size_t orow = ((size_t)(g * 16 + frow) * 512) * 1024 + cw * 64 + colL2;
  const size_t gslab = (size_t)g * 8192;
  const size_t srcoff = gslab + (size_t)w * 1024 + lane;

  for (int s = 0; s < 512; ++s) {
    // xw prefetch (cached, WG-private) -- issue before the poll
    const size_t oidx = orow + (size_t)s * 1024;
    float2 xwv = *(const float2*)&out[oidx];
    asm volatile("" : "+v"(xwv.x), "+v"(xwv.y));

    // poll-pull: initial full pull, then re-load only missing words
    const u64* src = ring + (size_t)(s & 3) * 32768 + srcoff;
    u64 hv[16];
#pragma unroll
    for (int t = 0; t < 4; ++t)
#pragma unroll
      for (int j2 = 0; j2 < 4; ++j2)
        hv[t * 4 + j2] = __hip_atomic_load(src + t * 256 + j2 * 64, __ATOMIC_RELAXED, SCOPE_AGENT);
    {
      int it = 0;
      while (true) {
        bool d = true;
#pragma unroll
        for (int i = 0; i < 16; ++i) d = d && (hv[i] != SENT);
        if (__all(d) || ++it >= (1 << 16)) break;
#pragma unroll
        for (int t = 0; t < 4; ++t)
#pragma unroll
          for (int j2 = 0; j2 < 4; ++j2)
            if (hv[t * 4 + j2] == SENT)
              hv[t * 4 + j2] =
                  __hip_atomic_load(src + t * 256 + j2 * 64, __ATOMIC_RELAXED, SCOPE_AGENT);
      }
    }

    f32x4 acc[4] = {};
#pragma unroll
    for (int t = 0; t < 4; ++t) {
      u64 w0 = hv[t * 4 + 0], w1 = hv[t * 4 + 1], w2 = hv[t * 4 + 2], w3 = hv[t * 4 + 3];
      i32x4 ahv, alv;
      ahv[0] = (int)__builtin_amdgcn_perm((u32)(w0 >> 32), (u32)w0, 0x07060302u);
      alv[0] = (int)__builtin_amdgcn_perm((u32)(w0 >> 32), (u32)w0, 0x05040100u);
      ahv[1] = (int)__builtin_amdgcn_perm((u32)(w1 >> 32), (u32)w1, 0x07060302u);
      alv[1] = (int)__builtin_amdgcn_perm((u32)(w1 >> 32), (u32)w1, 0x05040100u);
      ahv[2] = (int)__builtin_amdgcn_perm((u32)(w2 >> 32), (u32)w2, 0x07060302u);
      alv[2] = (int)__builtin_amdgcn_perm((u32)(w2 >> 32), (u32)w2, 0x05040100u);
      ahv[3] = (int)__builtin_amdgcn_perm((u32)(w3 >> 32), (u32)w3, 0x07060302u);
      alv[3] = (int)__builtin_amdgcn_perm((u32)(w3 >> 32), (u32)w3, 0x05040100u);
      bf16x8 ah = __builtin_bit_cast(bf16x8, ahv);
      bf16x8 al = __builtin_bit_cast(bf16x8, alv);
#pragma unroll
      for (int ct = 0; ct < 4; ++ct) {
        acc[ct] = __builtin_amdgcn_mfma_f32_16x16x32_bf16(al, __builtin_bit_cast(bf16x8, Bh_[ct][t]), acc[ct], 0, 0, 0);
        acc[ct] = __builtin_amdgcn_mfma_f32_16x16x32_bf16(ah, __builtin_bit_cast(bf16x8, Bl_[ct][t]), acc[ct], 0, 0, 0);
        acc[ct] = __builtin_amdgcn_mfma_f32_16x16x32_bf16(ah, __builtin_bit_cast(bf16x8, Bh_[ct][t]), acc[ct], 0, 0, 0);
      }
    }

    // partials -> LDS (parity-buffered; row_local = q*4+r, col_local = ct*16+colL)
#pragma unroll
    for (int ct = 0; ct < 4; ++ct)
#pragma unroll
      for (int r = 0; r < 4; ++r)
        Red[s & 1][w][(q * 4 + r) * RST + ct * 16 + colL] = acc[ct][r];
    __syncthreads();

    // final: reduce 8 K-partials for this thread's 2 outputs (row frow, cols colL2, colL2+1)
    float s0 = xwv.x, s1 = xwv.y;
#pragma unroll
    for (int ww = 0; ww < 8; ++ww) {
      float2 pr = *(const float2*)&Red[s & 1][ww][frow * RST + colL2];
      s0 += pr.x; s1 += pr.y;
    }
    float h0v = tanh_fast(s0), h1v = tanh_fast(s1);

    // publish h_{s+1} into ring[(s+1)&3]: wave-dense 8B stores (512B bursts)
    u64 val = (u64)pack_hl(h0v) | ((u64)pack_hl(h1v) << 32);
    __hip_atomic_store(ring + (size_t)((s + 1) & 3) * 32768 + gslab + pubI, val,
                       __ATOMIC_RELAXED, SCOPE_AGENT);
    // sentinel my word in the slot read last step (dense too)
    if (s > 0)
      __hip_atomic_store(ring + (size_t)((s - 1) & 3) * 32768 + gslab + pubI, SENT,
                         __ATOMIC_RELAXED, SCOPE_AGENT);
    // d_out store off the critical path (cached, WG-private)
    *(float2*)&out[oidx] = make_float2(h0v, h1v);
  }
}

// ---------- launch ----------
extern "C" void kernel_launch(void* const* d_in, const int* in_sizes, int n_in,
                              void* d_out, int out_size, void* d_ws, size_t ws_size,
                              hipStream_t stream) {
  const float* x    = (const float*)d_in[0];
  const float* h0   = (const float*)d_in[1];
  const float* Wx   = (const float*)d_in[2];
  const float* Wh   = (const float*)d_in[3];
  const float* bias = (const float*)d_in[4];
  float* out = (float*)d_out;
  char* ws = (char*)d_ws;

  const size_t MB2 = (size_t)1 << 21;
  u16* WxThi = (u16*)(ws);
  u16* WxTlo = (u16*)(ws + MB2);
  u16* WhThi = (u16*)(ws + 2 * MB2);
  u16* WhTlo = (u16*)(ws + 3 * MB2);
  u64* ring  = (u64*)(ws + 4 * MB2);  // 4 slots x 32768 u64 = 1 MB

  wsplit<<<dim3(32, 32), dim3(32, 8), 0, stream>>>(Wx, WxThi, WxTlo);
  wsplit<<<dim3(32, 32), dim3(32, 8), 0, stream>>>(Wh, WhThi, WhTlo);
  hinit<<<512, 256, 0, stream>>>(h0, ring);
  xw_gemm<<<dim3(8, 256), 256, 0, stream>>>(x, WxThi, WxTlo, bias, out);
  rnn_scan<<<64, 512, 0, stream>>>(WhThi, WhTlo, out, ring);
}

// Round 11
// 1578.671 us; speedup vs baseline: 3.7985x; 1.1842x over previous
//
#include <hip/hip_runtime.h>
#include <hip/hip_bf16.h>
#include <stdint.h>
#include <stddef.h>

typedef short bf16x8 __attribute__((ext_vector_type(8)));
typedef float f32x4 __attribute__((ext_vector_type(4)));
typedef int i32x4 __attribute__((ext_vector_type(4)));
typedef unsigned short u16;
typedef unsigned int u32;
typedef unsigned long long u64;

#define SCOPE_AGENT __HIP_MEMORY_SCOPE_AGENT
#define SENT 0xFFFFFFFFFFFFFFFFull

// ---------- helpers: fp32 -> bf16 (RNE) split ----------
__device__ __forceinline__ u16 f2bf(float x) {
  u32 u = __builtin_bit_cast(u32, x);
  u32 r = (u + 0x7fffu + ((u >> 16) & 1u)) >> 16;
  return (u16)r;
}
__device__ __forceinline__ float bf2f(u16 h) {
  u32 u = ((u32)h) << 16;
  return __builtin_bit_cast(float, u);
}
__device__ __forceinline__ void split2(float a, float b, u32& hw, u32& lw) {
  u16 ha = f2bf(a), hb = f2bf(b);
  float ra = a - bf2f(ha), rb = b - bf2f(hb);
  hw = (u32)ha | ((u32)hb << 16);
  lw = (u32)f2bf(ra) | ((u32)f2bf(rb) << 16);
}
// pack h value as (bf16_hi << 16) | bf16_lo (hi never 0xFFFF -> sentinel safe)
__device__ __forceinline__ u32 pack_hl(float v) {
  u16 hi = f2bf(v);
  u16 lo = f2bf(v - bf2f(hi));
  return ((u32)hi << 16) | (u32)lo;
}
__device__ __forceinline__ float tanh_fast(float x) {
  float xc = fminf(9.0f, fmaxf(-9.0f, x));
  float z = exp2f(xc * 2.8853900817779268f);  // e^{2x}
  return (z - 1.0f) * __builtin_amdgcn_rcpf(z + 1.0f);
}

// ---------- prep: transpose + bf16-split a 1024x1024 weight ----------
__global__ void wsplit(const float* __restrict__ W, u16* __restrict__ Thi, u16* __restrict__ Tlo) {
  __shared__ float tile[32][33];
  const int bx = blockIdx.x * 32;  // c base
  const int by = blockIdx.y * 32;  // k base
  const int tx = threadIdx.x, ty = threadIdx.y;  // (32,8)
#pragma unroll
  for (int r = 0; r < 4; ++r) {
    int ky = ty + 8 * r;
    tile[ky][tx] = W[(size_t)(by + ky) * 1024 + bx + tx];
  }
  __syncthreads();
#pragma unroll
  for (int r = 0; r < 4; ++r) {
    int row = ty + 8 * r;           // c-local
    float v = tile[tx][row];        // = W[by+tx][bx+row]
    u16 hi = f2bf(v);
    u16 lo = f2bf(v - bf2f(hi));
    Thi[(size_t)(bx + row) * 1024 + by + tx] = hi;
    Tlo[(size_t)(bx + row) * 1024 + by + tx] = lo;
  }
}

// ---------- prep: ring init ----------
// ring = 4 slots x (8 groups x 4096 u64). Slot 0 <- h0 in 8-row block-fragment
// layout: word (row in [0,8), kp=k/2 in [0,512)) at
//   I8 = (kp>>4)*128 + (kp&3)*32 + ((kp>>2)&3)*8 + row
// with kp = hi4*16 + q*4 + j2 (hi4=I8>>7, j2=(I8>>5)&3, q=(I8>>3)&3, row=I8&7).
// Slots 1..3 <- sentinel.
__global__ void hinit(const float* __restrict__ h0, u64* __restrict__ ring) {
  int i = blockIdx.x * 256 + threadIdx.x;  // 0..131071
  int slot = i >> 15, li = i & 32767;
  if (slot == 0) {
    int g = li >> 12, I8 = li & 4095;
    int row = I8 & 7, q = (I8 >> 3) & 3, j2 = (I8 >> 5) & 3, hi4 = I8 >> 7;
    int kp = hi4 * 16 + q * 4 + j2, k = kp * 2;
    int n = g * 8 + row;
    u64 val = (u64)pack_hl(h0[n * 1024 + k]) | ((u64)pack_hl(h0[n * 1024 + k + 1]) << 32);
    __hip_atomic_store(&ring[i], val, __ATOMIC_RELAXED, SCOPE_AGENT);
  } else {
    __hip_atomic_store(&ring[i], SENT, __ATOMIC_RELAXED, SCOPE_AGENT);
  }
}

// ---------- phase 1: xw = x @ Wx + b  (bf16x3 MFMA, 128x128 tile, BK=32) ----------
#define LDT 40  // padded LDS row stride (bf16 elems)

__global__ __launch_bounds__(256, 2) void xw_gemm(
    const float* __restrict__ X, const u16* __restrict__ BThi, const u16* __restrict__ BTlo,
    const float* __restrict__ bias, float* __restrict__ out) {
  __shared__ u16 Ah[128 * LDT], Al[128 * LDT], Bh[128 * LDT], Bl[128 * LDT];
  const int tid = threadIdx.x;
  const int lane = tid & 63, wave = tid >> 6;
  const int wm = wave >> 1, wn = wave & 1;
  const int m0 = blockIdx.y * 128, n0 = blockIdx.x * 128;
  const int arow = tid >> 1, afo = (tid & 1) << 4;
  const int bcol = tid >> 1, bko = (tid & 1) << 4;
  const float* Xa = X + (size_t)(m0 + arow) * 1024 + afo;
  const u16* bhp = BThi + (size_t)(n0 + bcol) * 1024 + bko;
  const u16* blp = BTlo + (size_t)(n0 + bcol) * 1024 + bko;

  f32x4 acc[4][4] = {};

  const int aoff = (wm * 64 + (lane & 15)) * LDT + ((lane >> 4) << 3);
  const int boff = (wn * 64 + (lane & 15)) * LDT + ((lane >> 4) << 3);

  for (int k0 = 0; k0 < 1024; k0 += 32) {
    const float4* xp = (const float4*)(Xa + k0);
    float4 f0 = xp[0], f1 = xp[1], f2 = xp[2], f3 = xp[3];
    i32x4 gbh0 = *(const i32x4*)(bhp + k0);
    i32x4 gbh1 = *(const i32x4*)(bhp + k0 + 8);
    i32x4 gbl0 = *(const i32x4*)(blp + k0);
    i32x4 gbl1 = *(const i32x4*)(blp + k0 + 8);
    u32 hw0, hw1, hw2, hw3, hw4, hw5, hw6, hw7;
    u32 lw0, lw1, lw2, lw3, lw4, lw5, lw6, lw7;
    split2(f0.x, f0.y, hw0, lw0); split2(f0.z, f0.w, hw1, lw1);
    split2(f1.x, f1.y, hw2, lw2); split2(f1.z, f1.w, hw3, lw3);
    split2(f2.x, f2.y, hw4, lw4); split2(f2.z, f2.w, hw5, lw5);
    split2(f3.x, f3.y, hw6, lw6); split2(f3.z, f3.w, hw7, lw7);
    __syncthreads();
    *(i32x4*)&Ah[arow * LDT + afo]     = i32x4{(int)hw0, (int)hw1, (int)hw2, (int)hw3};
    *(i32x4*)&Ah[arow * LDT + afo + 8] = i32x4{(int)hw4, (int)hw5, (int)hw6, (int)hw7};
    *(i32x4*)&Al[arow * LDT + afo]     = i32x4{(int)lw0, (int)lw1, (int)lw2, (int)lw3};
    *(i32x4*)&Al[arow * LDT + afo + 8] = i32x4{(int)lw4, (int)lw5, (int)lw6, (int)lw7};
    *(i32x4*)&Bh[bcol * LDT + bko]     = gbh0;
    *(i32x4*)&Bh[bcol * LDT + bko + 8] = gbh1;
    *(i32x4*)&Bl[bcol * LDT + bko]     = gbl0;
    *(i32x4*)&Bl[bcol * LDT + bko + 8] = gbl1;
    __syncthreads();

    bf16x8 a_h[4], a_l[4], b_h[4], b_l[4];
#pragma unroll
    for (int i = 0; i < 4; ++i) {
      a_h[i] = *(const bf16x8*)(Ah + aoff + i * 16 * LDT);
      a_l[i] = *(const bf16x8*)(Al + aoff + i * 16 * LDT);
      b_h[i] = *(const bf16x8*)(Bh + boff + i * 16 * LDT);
      b_l[i] = *(const bf16x8*)(Bl + boff + i * 16 * LDT);
    }
#pragma unroll
    for (int i = 0; i < 4; ++i)
#pragma unroll
      for (int j = 0; j < 4; ++j)
        acc[i][j] = __builtin_amdgcn_mfma_f32_16x16x32_bf16(a_h[i], b_h[j], acc[i][j], 0, 0, 0);
#pragma unroll
    for (int i = 0; i < 4; ++i)
#pragma unroll
      for (int j = 0; j < 4; ++j)
        acc[i][j] = __builtin_amdgcn_mfma_f32_16x16x32_bf16(a_h[i], b_l[j], acc[i][j], 0, 0, 0);
#pragma unroll
    for (int i = 0; i < 4; ++i)
#pragma unroll
      for (int j = 0; j < 4; ++j)
        acc[i][j] = __builtin_amdgcn_mfma_f32_16x16x32_bf16(a_l[i], b_h[j], acc[i][j], 0, 0, 0);
  }
  const int ccol = n0 + wn * 64 + (lane & 15);
  const int crow = m0 + wm * 64 + ((lane >> 4) << 2);
#pragma unroll
  for (int j = 0; j < 4; ++j) {
    float bv = bias[ccol + j * 16];
#pragma unroll
    for (int i = 0; i < 4; ++i)
#pragma unroll
      for (int r = 0; r < 4; ++r)
        out[(size_t)(crow + i * 16 + r) * 1024 + ccol + j * 16] = acc[i][j][r] + bv;
  }
}

// ---------- phase 2: sequential scan, flagless ring-4, 8-row groups ----------
// 128 WGs x 512 thr. WG (g,cw): rows [8g,8g+8), cols [64cw,64cw+64).
// Wave w owns K-eighth [128w,128w+128); B pinned via inline-asm loads.
// Pull = 8 u64/lane: lanes colL<8 load j2 in {0,1}, colL>=8 load j2 in {2,3}
// for the SAME (q,row=colL&7) words; the 8-word poll therefore covers EVERY
// word the wave consumes (this closes R10's race: R10 polled j2 {0,1} and
// blindly loaded {2,3}, whose producer-side stores are independent). After
// the poll converges, a shfl_xor(lane^8) exchange rebuilds all 4 j2 per lane.
// Publish: dense 2KB block by tid<256. Ring-4 sentinel/clear protocol as R8/R9.
#define RST 68  // padded Red row stride (floats)

__global__ __launch_bounds__(512, 2) void rnn_scan(
    const u16* __restrict__ WThi, const u16* __restrict__ WTlo,
    float* __restrict__ out, u64* __restrict__ ring) {
  __shared__ float Red[2][8][8 * RST];
  const int tid = threadIdx.x;
  const int lane = tid & 63, w = tid >> 6;   // w = K-eighth
  const int cw = blockIdx.x & 15, g = blockIdx.x >> 4;
  const int colL = lane & 15, q = lane >> 4;

  // ---- B -> registers/AGPRs via inline asm (never rematerialized) ----
  i32x4 Bh_[4][4], Bl_[4][4];
#pragma unroll
  for (int ct = 0; ct < 4; ++ct) {
    const u16* bhp = WThi + (size_t)(cw * 64 + ct * 16 + colL) * 1024 + w * 128 + (q << 3);
    const u16* blp = WTlo + (size_t)(cw * 64 + ct * 16 + colL) * 1024 + w * 128 + (q << 3);
#pragma unroll
    for (int t = 0; t < 4; ++t) {
      asm volatile("global_load_dwordx4 %0, %1, off" : "=v"(Bh_[ct][t]) : "v"(bhp + t * 32));
      asm volatile("global_load_dwordx4 %0, %1, off" : "=v"(Bl_[ct][t]) : "v"(blp + t * 32));
    }
  }
  asm volatile("s_waitcnt vmcnt(0)" ::: "memory");
  __builtin_amdgcn_sched_barrier(0);

  // final-phase constants (tid<256): dense word pubI = cw*256 + tid.
  // tid bits: row=2:0, q2=4:3, j2b=6:5, b=7 -> kp=(2cw+b)*16+q2*4+j2b,
  // kloc = 2kp-64cw = 32b+8q2+2j2b (always < 64 for tid<256).
  const int frow = tid & 7;
  const int kloc = 32 * (tid >> 7) + 8 * ((tid >> 3) & 3) + 2 * ((tid >> 5) & 3);
  const bool fin = tid < 256;
  const size_t pubI = (size_t)cw * 256 + tid;                  // dense (tid<256)
  const size_t orow = ((size_t)(g * 8 + frow) * 512) * 1024 + cw * 64 + kloc;
  const size_t gslab = (size_t)g * 4096;
  // this lane's 2 owned j2 values: {j2o, j2o+1}
  const int j2o = (colL >> 3) * 2;
  const size_t srcoff = gslab + (size_t)w * 512 + (q << 3) + (colL & 7);

  for (int s = 0; s < 512; ++s) {
    // xw prefetch (cached, WG-private) -- issue before the poll
    const size_t oidx = orow + (size_t)s * 1024;
    float2 xwv = make_float2(0.f, 0.f);
    if (fin) {
      xwv = *(const float2*)&out[oidx];
      asm volatile("" : "+v"(xwv.x), "+v"(xwv.y));
    }

    // poll-pull: 8 owned words; selective re-load of still-sentinel words.
    // __all over the wave verifies every word the wave will consume.
    const u64* src = ring + (size_t)(s & 3) * 32768 + srcoff;
    u64 hv[8];
#pragma unroll
    for (int t = 0; t < 4; ++t)
#pragma unroll
      for (int i = 0; i < 2; ++i)
        hv[t * 2 + i] =
            __hip_atomic_load(src + t * 128 + (j2o + i) * 32, __ATOMIC_RELAXED, SCOPE_AGENT);
    {
      int it = 0;
      while (true) {
        bool d = true;
#pragma unroll
        for (int i = 0; i < 8; ++i) d = d && (hv[i] != SENT);
        if (__all(d) || ++it >= (1 << 16)) break;
#pragma unroll
        for (int t = 0; t < 4; ++t)
#pragma unroll
          for (int i = 0; i < 2; ++i)
            if (hv[t * 2 + i] == SENT)
              hv[t * 2 + i] =
                  __hip_atomic_load(src + t * 128 + (j2o + i) * 32, __ATOMIC_RELAXED, SCOPE_AGENT);
      }
    }

    const bool hi8 = (colL & 8) != 0;
    f32x4 acc[4] = {};
#pragma unroll
    for (int t = 0; t < 4; ++t) {
      // partner exchange: lane^8 holds the other j2 pair for the same (q,row)
      u64 a0 = hv[t * 2 + 0], a1 = hv[t * 2 + 1];
      u64 p0 = __shfl_xor((unsigned long long)a0, 8);
      u64 p1 = __shfl_xor((unsigned long long)a1, 8);
      u64 w0 = hi8 ? p0 : a0;
      u64 w1 = hi8 ? p1 : a1;
      u64 w2 = hi8 ? a0 : p0;
      u64 w3 = hi8 ? a1 : p1;
      i32x4 ahv, alv;
      ahv[0] = (int)__builtin_amdgcn_perm((u32)(w0 >> 32), (u32)w0, 0x07060302u);
      alv[0] = (int)__builtin_amdgcn_perm((u32)(w0 >> 32), (u32)w0, 0x05040100u);
      ahv[1] = (int)__builtin_amdgcn_perm((u32)(w1 >> 32), (u32)w1, 0x07060302u);
      alv[1] = (int)__builtin_amdgcn_perm((u32)(w1 >> 32), (u32)w1, 0x05040100u);
      ahv[2] = (int)__builtin_amdgcn_perm((u32)(w2 >> 32), (u32)w2, 0x07060302u);
      alv[2] = (int)__builtin_amdgcn_perm((u32)(w2 >> 32), (u32)w2, 0x05040100u);
      ahv[3] = (int)__builtin_amdgcn_perm((u32)(w3 >> 32), (u32)w3, 0x07060302u);
      alv[3] = (int)__builtin_amdgcn_perm((u32)(w3 >> 32), (u32)w3, 0x05040100u);
      bf16x8 ah = __builtin_bit_cast(bf16x8, ahv);
      bf16x8 al = __builtin_bit_cast(bf16x8, alv);
#pragma unroll
      for (int ct = 0; ct < 4; ++ct) {
        acc[ct] = __builtin_amdgcn_mfma_f32_16x16x32_bf16(al, __builtin_bit_cast(bf16x8, Bh_[ct][t]), acc[ct], 0, 0, 0);
        acc[ct] = __builtin_amdgcn_mfma_f32_16x16x32_bf16(ah, __builtin_bit_cast(bf16x8, Bl_[ct][t]), acc[ct], 0, 0, 0);
        acc[ct] = __builtin_amdgcn_mfma_f32_16x16x32_bf16(ah, __builtin_bit_cast(bf16x8, Bh_[ct][t]), acc[ct], 0, 0, 0);
      }
    }

    // partials -> LDS: C rows 8-15 duplicate rows 0-7 (A-row dup), store q<2
    if (q < 2) {
#pragma unroll
      for (int ct = 0; ct < 4; ++ct)
#pragma unroll
        for (int r = 0; r < 4; ++r)
          Red[s & 1][w][(q * 4 + r) * RST + ct * 16 + colL] = acc[ct][r];
    }
    __syncthreads();

    if (fin) {
      // final: reduce 8 K-partials for outputs (frow, kloc), (frow, kloc+1)
      float s0 = xwv.x, s1 = xwv.y;
#pragma unroll
      for (int ww = 0; ww < 8; ++ww) {
        float2 pr = *(const float2*)&Red[s & 1][ww][frow * RST + kloc];
        s0 += pr.x; s1 += pr.y;
      }
      float h0v = tanh_fast(s0), h1v = tanh_fast(s1);

      // publish h_{s+1} into ring[(s+1)&3]: dense 2KB block per WG
      u64 val = (u64)pack_hl(h0v) | ((u64)pack_hl(h1v) << 32);
      __hip_atomic_store(ring + (size_t)((s + 1) & 3) * 32768 + gslab + pubI, val,
                         __ATOMIC_RELAXED, SCOPE_AGENT);
      // sentinel my word in the slot read last step (same thread republishes
      // this word at s+2; program order + the step-(s+1) pull vmcnt drains it)
      if (s > 0)
        __hip_atomic_store(ring + (size_t)((s - 1) & 3) * 32768 + gslab + pubI, SENT,
                           __ATOMIC_RELAXED, SCOPE_AGENT);
      *(float2*)&out[oidx] = make_float2(h0v, h1v);
    }
  }
}

// ---------- launch ----------
extern "C" void kernel_launch(void* const* d_in, const int* in_sizes, int n_in,
                              void* d_out, int out_size, void* d_ws, size_t ws_size,
                              hipStream_t stream) {
  const float* x    = (const float*)d_in[0];
  const float* h0   = (const float*)d_in[1];
  const float* Wx   = (const float*)d_in[2];
  const float* Wh   = (const float*)d_in[3];
  const float* bias = (const float*)d_in[4];
  float* out = (float*)d_out;
  char* ws = (char*)d_ws;

  const size_t MB2 = (size_t)1 << 21;
  u16* WxThi = (u16*)(ws);
  u16* WxTlo = (u16*)(ws + MB2);
  u16* WhThi = (u16*)(ws + 2 * MB2);
  u16* WhTlo = (u16*)(ws + 3 * MB2);
  u64* ring  = (u64*)(ws + 4 * MB2);  // 4 slots x 32768 u64 = 1 MB

  wsplit<<<dim3(32, 32), dim3(32, 8), 0, stream>>>(Wx, WxThi, WxTlo);
  wsplit<<<dim3(32, 32), dim3(32, 8), 0, stream>>>(Wh, WhThi, WhTlo);
  hinit<<<512, 256, 0, stream>>>(h0, ring);
  xw_gemm<<<dim3(8, 256), 256, 0, stream>>>(x, WxThi, WxTlo, bias, out);
  rnn_scan<<<128, 512, 0, stream>>>(WhThi, WhTlo, out, ring);
}